// Round 10
// baseline (76.227 us; speedup 1.0000x reference)
//
#include <hip/hip_runtime.h>

#define B_   4
#define C_   256
#define CR_  64
#define H_   128
#define W_   128
#define HW_  (H_ * W_)
#define G_   16
#define GC_  16
#define KO_  144   // K*K*G = 9*16
#define EPS_ 1e-5f

typedef __bf16 bf16x8 __attribute__((ext_vector_type(8)));
typedef __bf16 bf16x2 __attribute__((ext_vector_type(2)));
typedef float  f32x4  __attribute__((ext_vector_type(4)));

#define SX  66   // LDS row stride (bf16 elems) for xs/hbuf
#define WKL 68   // LDS row stride (f32) for wk tile: 272 B -> 16B-aligned rows

// ---------------------------------------------------------------------------
// prep: build MFMA A-fragments (lane order: m = lane&15, kslot = 8*(lane>>4)+j;
// the kslot permutation cancels between A and B since both use it).
// ---------------------------------------------------------------------------
__global__ void prep_kernel(const float* __restrict__ w1,
                            const float* __restrict__ gamma,
                            const float* __restrict__ beta,
                            const float* __restrict__ mean,
                            const float* __restrict__ var,
                            const float* __restrict__ w2,
                            __bf16* __restrict__ w1frag,
                            __bf16* __restrict__ w2frag,
                            float* __restrict__ bias2) {
    int idx = blockIdx.x * 256 + threadIdx.x;
    if (idx < 16384) {                      // w1frag: [8 kc][4 mt][64 l][8 j]
        int kc = idx >> 11, r = idx & 2047;
        int mt = r >> 9, l = (r >> 3) & 63, j = r & 7;
        int o = mt * 16 + (l & 15);
        int c = kc * 32 + 8 * (l >> 4) + j;
        float alpha = gamma[o] * rsqrtf(var[o] + EPS_);
        w1frag[idx] = (__bf16)(w1[o * C_ + c] * alpha);
        if (idx < CR_) {
            float a2 = gamma[idx] * rsqrtf(var[idx] + EPS_);
            bias2[idx] = beta[idx] - mean[idx] * a2;
        }
    } else if (idx < 16384 + 9216) {        // w2frag: [9 mt][2 kc2][64 l][8 j]
        int i2 = idx - 16384;
        int mt = i2 >> 10, r = i2 & 1023;
        int kc2 = r >> 9, l = (r >> 3) & 63, j = r & 7;
        int o2 = mt * 16 + (l & 15);
        int cc = kc2 * 32 + 8 * (l >> 4) + j;
        w2frag[i2] = (__bf16)(w2[o2 * CR_ + cc]);
    }
}

// ---------------------------------------------------------------------------
// FULLY FUSED: conv1(+BN+ReLU) + conv2 + involution. Block = 64-px row tile.
// Phase 1: h[64][64] via bf16 MFMA (x staged per-32K chunk, double-buffered).
// Phase 2: wk[144][64] via bf16 MFMA -> stored to LDS (never HBM).
// Phase 3: involution from LDS wk + global x (rows h-1..h+1, L2/L3-hot).
// LDS: 39 KB (wkl overlays xs+hbuf after phase 2) -> 4 blocks/CU.
// ---------------------------------------------------------------------------
__global__ __launch_bounds__(256, 4) void fused_kernel(
        const float* __restrict__ x,
        const __bf16* __restrict__ w1frag,
        const float* __restrict__ bias2,
        const __bf16* __restrict__ w2frag,
        const float* __restrict__ b2,
        float* __restrict__ out) {
    __shared__ __align__(16) char smem[KO_ * WKL * 4];   // 39168 B
    __bf16* xs   = (__bf16*)smem;              // [2*32*SX] = 8448 B
    __bf16* hbuf = (__bf16*)(smem + 8448);     // [64*SX]   = 8448 B
    float*  wkl  = (float*)smem;               // [144][WKL] (after phase 2)

    const int tid  = threadIdx.x;
    const int lane = tid & 63;
    const int wave = tid >> 6;
    const int wm = wave >> 1, wn = wave & 1;
    const int g = lane >> 4, n = lane & 15;

    const int px0 = blockIdx.x * 64;
    const int b   = px0 >> 14;
    const int hw0 = px0 & (HW_ - 1);

    const float* xb = x + (size_t)b * C_ * HW_ + hw0;
    const int krow = tid >> 3;             // 0..31 (k row within chunk)
    const int t8   = tid & 7;              // 0..7

    // ---- stage chunk 0 into buf 0 ----
    {
        float4 v0 = *(const float4*)&xb[(size_t)krow * HW_ + 4 * t8];
        float4 v1 = *(const float4*)&xb[(size_t)krow * HW_ + 32 + 4 * t8];
        __bf16* d0 = &xs[krow * SX + 4 * t8];
        __bf16* d1 = &xs[krow * SX + 32 + 4 * t8];
        *(bf16x2*)&d0[0] = bf16x2{(__bf16)v0.x, (__bf16)v0.y};
        *(bf16x2*)&d0[2] = bf16x2{(__bf16)v0.z, (__bf16)v0.w};
        *(bf16x2*)&d1[0] = bf16x2{(__bf16)v1.x, (__bf16)v1.y};
        *(bf16x2*)&d1[2] = bf16x2{(__bf16)v1.z, (__bf16)v1.w};
    }
    __syncthreads();

    // ======================= phase 1: conv1 ============================
    f32x4 acc1[2][2];
#pragma unroll
    for (int m = 0; m < 2; ++m)
#pragma unroll
        for (int t = 0; t < 2; ++t) acc1[m][t] = f32x4{0.f, 0.f, 0.f, 0.f};

    for (int kc = 0; kc < 8; ++kc) {
        const int buf = kc & 1;
        float4 nf0, nf1;
        if (kc < 7) {   // issue next chunk's loads early
            nf0 = *(const float4*)&xb[(size_t)(32 * (kc + 1) + krow) * HW_ + 4 * t8];
            nf1 = *(const float4*)&xb[(size_t)(32 * (kc + 1) + krow) * HW_ + 32 + 4 * t8];
        }
        bf16x8 a0 = *(const bf16x8*)&w1frag[((kc * 4 + 2 * wm + 0) * 64 + lane) * 8];
        bf16x8 a1 = *(const bf16x8*)&w1frag[((kc * 4 + 2 * wm + 1) * 64 + lane) * 8];
        const int base = buf * (32 * SX);
        bf16x8 b0, b1;
#pragma unroll
        for (int j = 0; j < 8; ++j) {
            b0[j] = xs[base + (8 * g + j) * SX + (2 * wn + 0) * 16 + n];
            b1[j] = xs[base + (8 * g + j) * SX + (2 * wn + 1) * 16 + n];
        }
        acc1[0][0] = __builtin_amdgcn_mfma_f32_16x16x32_bf16(a0, b0, acc1[0][0], 0, 0, 0);
        acc1[0][1] = __builtin_amdgcn_mfma_f32_16x16x32_bf16(a0, b1, acc1[0][1], 0, 0, 0);
        acc1[1][0] = __builtin_amdgcn_mfma_f32_16x16x32_bf16(a1, b0, acc1[1][0], 0, 0, 0);
        acc1[1][1] = __builtin_amdgcn_mfma_f32_16x16x32_bf16(a1, b1, acc1[1][1], 0, 0, 0);

        if (kc < 7) {
            __bf16* d0 = &xs[(buf ^ 1) * (32 * SX) + krow * SX + 4 * t8];
            __bf16* d1 = &xs[(buf ^ 1) * (32 * SX) + krow * SX + 32 + 4 * t8];
            *(bf16x2*)&d0[0] = bf16x2{(__bf16)nf0.x, (__bf16)nf0.y};
            *(bf16x2*)&d0[2] = bf16x2{(__bf16)nf0.z, (__bf16)nf0.w};
            *(bf16x2*)&d1[0] = bf16x2{(__bf16)nf1.x, (__bf16)nf1.y};
            *(bf16x2*)&d1[2] = bf16x2{(__bf16)nf1.z, (__bf16)nf1.w};
        }
        __syncthreads();
    }

    // bias + relu -> hbuf (bf16). D elem: o = Mt*16+4g+j, px = Nt*16+n
#pragma unroll
    for (int m = 0; m < 2; ++m) {
        const int Mo = (2 * wm + m) * 16 + 4 * g;
        float4 bv = *(const float4*)&bias2[Mo];
        float bj[4] = {bv.x, bv.y, bv.z, bv.w};
#pragma unroll
        for (int t = 0; t < 2; ++t) {
            const int px = (2 * wn + t) * 16 + n;
#pragma unroll
            for (int j = 0; j < 4; ++j) {
                hbuf[(Mo + j) * SX + px] = (__bf16)fmaxf(acc1[m][t][j] + bj[j], 0.f);
            }
        }
    }
    __syncthreads();

    // ======================= phase 2: conv2 ============================
    f32x4 acc2[9];
#pragma unroll
    for (int m = 0; m < 9; ++m) acc2[m] = f32x4{0.f, 0.f, 0.f, 0.f};

#pragma unroll
    for (int kc2 = 0; kc2 < 2; ++kc2) {
        bf16x8 hb;
#pragma unroll
        for (int j = 0; j < 8; ++j)
            hb[j] = hbuf[(kc2 * 32 + 8 * g + j) * SX + wave * 16 + n];
#pragma unroll
        for (int mt = 0; mt < 9; ++mt) {
            bf16x8 a = *(const bf16x8*)&w2frag[((mt * 2 + kc2) * 64 + lane) * 8];
            acc2[mt] = __builtin_amdgcn_mfma_f32_16x16x32_bf16(a, hb, acc2[mt], 0, 0, 0);
        }
    }

    __syncthreads();   // all hbuf/xs reads done -> safe to overlay wkl

    // store wk tile (+bias) to LDS: row o2 = mt*16+4g+j, col = wave*16+n
#pragma unroll
    for (int mt = 0; mt < 9; ++mt) {
        const int o0 = mt * 16 + 4 * g;
        float4 bv = *(const float4*)&b2[o0];
        float bj[4] = {bv.x, bv.y, bv.z, bv.w};
#pragma unroll
        for (int j = 0; j < 4; ++j)
            wkl[(o0 + j) * WKL + wave * 16 + n] = acc2[mt][j] + bj[j];
    }
    __syncthreads();

    // ======================= phase 3: involution ========================
    // thread = (gg = tid>>4, ch2 = (tid>>3)&1, q8 = tid&7): 8 px x 8 channels
    const int gg  = tid >> 4;
    const int ch2 = (tid >> 3) & 1;
    const int q8  = tid & 7;
    const int po  = q8 * 8;
    const int hrow = hw0 >> 7;
    const int wcol = (hw0 & (W_ - 1)) + po;

    float wkr[9][8];
#pragma unroll
    for (int k = 0; k < 9; ++k) {
        float4 aa = *(const float4*)&wkl[(gg * 9 + k) * WKL + po];
        float4 bb = *(const float4*)&wkl[(gg * 9 + k) * WKL + po + 4];
        wkr[k][0] = aa.x; wkr[k][1] = aa.y; wkr[k][2] = aa.z; wkr[k][3] = aa.w;
        wkr[k][4] = bb.x; wkr[k][5] = bb.y; wkr[k][6] = bb.z; wkr[k][7] = bb.w;
    }

    const bool hok0 = (hrow > 0), hok2 = (hrow < H_ - 1);
    const bool okl  = (wcol > 0), okr  = (wcol < W_ - 8);

    const size_t pxbase = (size_t)b * C_ * HW_ + (size_t)hrow * W_ + wcol;
    const int ch0 = gg * GC_ + ch2 * 8;

#pragma unroll 2
    for (int i = 0; i < 8; ++i) {
        const float* xc = x + pxbase + (size_t)(ch0 + i) * HW_;
        float acc[8];
#pragma unroll
        for (int j = 0; j < 8; ++j) acc[j] = 0.f;
#pragma unroll
        for (int r = 0; r < 3; ++r) {
            if ((r == 0 && !hok0) || (r == 2 && !hok2)) continue;
            const float* rp = xc + (r - 1) * W_;
            float4 ea = *(const float4*)rp;
            float4 eb = *(const float4*)(rp + 4);
            float el = okl ? rp[-1] : 0.f;
            float er = okr ? rp[8] : 0.f;
            float e[10] = {el, ea.x, ea.y, ea.z, ea.w,
                           eb.x, eb.y, eb.z, eb.w, er};
#pragma unroll
            for (int j = 0; j < 8; ++j) {
                acc[j] = fmaf(wkr[3 * r + 0][j], e[j],     acc[j]);
                acc[j] = fmaf(wkr[3 * r + 1][j], e[j + 1], acc[j]);
                acc[j] = fmaf(wkr[3 * r + 2][j], e[j + 2], acc[j]);
            }
        }
        float* od = out + pxbase + (size_t)(ch0 + i) * HW_;
        *(float4*)&od[0] = float4{acc[0], acc[1], acc[2], acc[3]};
        *(float4*)&od[4] = float4{acc[4], acc[5], acc[6], acc[7]};
    }
}

// ---------------------------------------------------------------------------
extern "C" void kernel_launch(void* const* d_in, const int* in_sizes, int n_in,
                              void* d_out, int out_size, void* d_ws, size_t ws_size,
                              hipStream_t stream) {
    const float* x     = (const float*)d_in[0];
    const float* w1    = (const float*)d_in[1];
    const float* gamma = (const float*)d_in[2];
    const float* beta  = (const float*)d_in[3];
    const float* mean  = (const float*)d_in[4];
    const float* var   = (const float*)d_in[5];
    const float* w2    = (const float*)d_in[6];
    const float* b2    = (const float*)d_in[7];
    float* out = (float*)d_out;

    char* ws = (char*)d_ws;
    __bf16* w1frag = (__bf16*)(ws);                 // 32 KB [8][4][64][8]
    __bf16* w2frag = (__bf16*)(ws + (32 << 10));    // 18 KB [9][2][64][8]
    float*  bias2  = (float*)(ws + (56 << 10));     // 256 B

    hipLaunchKernelGGL(prep_kernel, dim3(100), dim3(256), 0, stream,
                       w1, gamma, beta, mean, var, w2, w1frag, w2frag, bias2);
    hipLaunchKernelGGL(fused_kernel, dim3(1024), dim3(256), 0, stream,
                       x, w1frag, bias2, w2frag, b2, out);
}

// Round 11
// 70.063 us; speedup vs baseline: 1.0880x; 1.0880x over previous
//
#include <hip/hip_runtime.h>

#define B_   4
#define C_   256
#define CR_  64
#define H_   128
#define W_   128
#define HW_  (H_ * W_)
#define G_   16
#define GC_  16
#define KO_  144   // K*K*G = 9*16
#define EPS_ 1e-5f

typedef __bf16 bf16x8 __attribute__((ext_vector_type(8)));
typedef __bf16 bf16x2 __attribute__((ext_vector_type(2)));
typedef float  f32x4  __attribute__((ext_vector_type(4)));

#define SX 66   // LDS row stride (elements) for xs/hbuf: banks 2-way on gathers

// ---------------------------------------------------------------------------
// prep: build MFMA A-fragments (lane order: m = lane&15, kslot = 8*(lane>>4)+j;
// the kslot permutation cancels between A and B since both use it).
// ---------------------------------------------------------------------------
__global__ void prep_kernel(const float* __restrict__ w1,
                            const float* __restrict__ gamma,
                            const float* __restrict__ beta,
                            const float* __restrict__ mean,
                            const float* __restrict__ var,
                            const float* __restrict__ w2,
                            __bf16* __restrict__ w1frag,
                            __bf16* __restrict__ w2frag,
                            float* __restrict__ bias2) {
    int idx = blockIdx.x * 256 + threadIdx.x;
    if (idx < 16384) {                      // w1frag: [8 kc][4 mt][64 l][8 j]
        int kc = idx >> 11, r = idx & 2047;
        int mt = r >> 9, l = (r >> 3) & 63, j = r & 7;
        int o = mt * 16 + (l & 15);
        int c = kc * 32 + 8 * (l >> 4) + j;
        float alpha = gamma[o] * rsqrtf(var[o] + EPS_);
        w1frag[idx] = (__bf16)(w1[o * C_ + c] * alpha);
        if (idx < CR_) {
            float a2 = gamma[idx] * rsqrtf(var[idx] + EPS_);
            bias2[idx] = beta[idx] - mean[idx] * a2;
        }
    } else if (idx < 16384 + 9216) {        // w2frag: [9 mt][2 kc2][64 l][8 j]
        int i2 = idx - 16384;
        int mt = i2 >> 10, r = i2 & 1023;
        int kc2 = r >> 9, l = (r >> 3) & 63, j = r & 7;
        int o2 = mt * 16 + (l & 15);
        int cc = kc2 * 32 + 8 * (l >> 4) + j;
        w2frag[i2] = (__bf16)(w2[o2 * CR_ + cc]);
    }
}

// ---------------------------------------------------------------------------
// fused conv1(+BN+ReLU) + conv2 via bf16 MFMA, fp32 accumulate.
// (R4/R5 version — ~22 us, near its x+wk HBM floor)
// ---------------------------------------------------------------------------
__global__ __launch_bounds__(256, 4) void conv12_kernel(
        const float* __restrict__ x,
        const __bf16* __restrict__ w1frag,
        const float* __restrict__ bias2,
        const __bf16* __restrict__ w2frag,
        const float* __restrict__ b2,
        float* __restrict__ wk) {
    __shared__ __bf16 xs[2 * 32 * SX];     // 8.4 KB double-buffered x chunk
    __shared__ __bf16 hbuf[CR_ * SX];      // 8.4 KB h tile (bf16)

    const int tid  = threadIdx.x;
    const int lane = tid & 63;
    const int wave = tid >> 6;
    const int wm = wave >> 1, wn = wave & 1;
    const int g = lane >> 4, n = lane & 15;

    const int px0 = blockIdx.x * 64;
    const int b   = px0 >> 14;
    const int hw0 = px0 & (HW_ - 1);

    const float* xb = x + (size_t)b * C_ * HW_ + hw0;
    const int krow = tid >> 3;             // 0..31 (k row within chunk)
    const int t8   = tid & 7;              // 0..7

    // ---- stage chunk 0 into buf 0 ----
    {
        float4 v0 = *(const float4*)&xb[(size_t)krow * HW_ + 4 * t8];
        float4 v1 = *(const float4*)&xb[(size_t)krow * HW_ + 32 + 4 * t8];
        __bf16* d0 = &xs[krow * SX + 4 * t8];
        __bf16* d1 = &xs[krow * SX + 32 + 4 * t8];
        *(bf16x2*)&d0[0] = bf16x2{(__bf16)v0.x, (__bf16)v0.y};
        *(bf16x2*)&d0[2] = bf16x2{(__bf16)v0.z, (__bf16)v0.w};
        *(bf16x2*)&d1[0] = bf16x2{(__bf16)v1.x, (__bf16)v1.y};
        *(bf16x2*)&d1[2] = bf16x2{(__bf16)v1.z, (__bf16)v1.w};
    }
    __syncthreads();

    // ======================= phase 1 ============================
    f32x4 acc1[2][2];
#pragma unroll
    for (int m = 0; m < 2; ++m)
#pragma unroll
        for (int t = 0; t < 2; ++t) acc1[m][t] = f32x4{0.f, 0.f, 0.f, 0.f};

    for (int kc = 0; kc < 8; ++kc) {
        const int buf = kc & 1;
        float4 nf0, nf1;
        if (kc < 7) {   // issue next chunk's loads early (hide HBM latency)
            nf0 = *(const float4*)&xb[(size_t)(32 * (kc + 1) + krow) * HW_ + 4 * t8];
            nf1 = *(const float4*)&xb[(size_t)(32 * (kc + 1) + krow) * HW_ + 32 + 4 * t8];
        }
        bf16x8 a0 = *(const bf16x8*)&w1frag[((kc * 4 + 2 * wm + 0) * 64 + lane) * 8];
        bf16x8 a1 = *(const bf16x8*)&w1frag[((kc * 4 + 2 * wm + 1) * 64 + lane) * 8];
        const int base = buf * (32 * SX);
        bf16x8 b0, b1;
#pragma unroll
        for (int j = 0; j < 8; ++j) {
            b0[j] = xs[base + (8 * g + j) * SX + (2 * wn + 0) * 16 + n];
            b1[j] = xs[base + (8 * g + j) * SX + (2 * wn + 1) * 16 + n];
        }
        acc1[0][0] = __builtin_amdgcn_mfma_f32_16x16x32_bf16(a0, b0, acc1[0][0], 0, 0, 0);
        acc1[0][1] = __builtin_amdgcn_mfma_f32_16x16x32_bf16(a0, b1, acc1[0][1], 0, 0, 0);
        acc1[1][0] = __builtin_amdgcn_mfma_f32_16x16x32_bf16(a1, b0, acc1[1][0], 0, 0, 0);
        acc1[1][1] = __builtin_amdgcn_mfma_f32_16x16x32_bf16(a1, b1, acc1[1][1], 0, 0, 0);

        if (kc < 7) {
            __bf16* d0 = &xs[(buf ^ 1) * (32 * SX) + krow * SX + 4 * t8];
            __bf16* d1 = &xs[(buf ^ 1) * (32 * SX) + krow * SX + 32 + 4 * t8];
            *(bf16x2*)&d0[0] = bf16x2{(__bf16)nf0.x, (__bf16)nf0.y};
            *(bf16x2*)&d0[2] = bf16x2{(__bf16)nf0.z, (__bf16)nf0.w};
            *(bf16x2*)&d1[0] = bf16x2{(__bf16)nf1.x, (__bf16)nf1.y};
            *(bf16x2*)&d1[2] = bf16x2{(__bf16)nf1.z, (__bf16)nf1.w};
        }
        __syncthreads();
    }

    // bias + relu -> hbuf (bf16). D elem: o = Mt*16+4g+j, px = Nt*16+n
#pragma unroll
    for (int m = 0; m < 2; ++m) {
        const int Mo = (2 * wm + m) * 16 + 4 * g;
        float4 bv = *(const float4*)&bias2[Mo];
        float bj[4] = {bv.x, bv.y, bv.z, bv.w};
#pragma unroll
        for (int t = 0; t < 2; ++t) {
            const int px = (2 * wn + t) * 16 + n;
#pragma unroll
            for (int j = 0; j < 4; ++j) {
                hbuf[(Mo + j) * SX + px] = (__bf16)fmaxf(acc1[m][t][j] + bj[j], 0.f);
            }
        }
    }
    __syncthreads();

    // ======================= phase 2 ============================
    f32x4 acc2[9];
#pragma unroll
    for (int m = 0; m < 9; ++m) acc2[m] = f32x4{0.f, 0.f, 0.f, 0.f};

#pragma unroll
    for (int kc2 = 0; kc2 < 2; ++kc2) {
        bf16x8 hb;
#pragma unroll
        for (int j = 0; j < 8; ++j)
            hb[j] = hbuf[(kc2 * 32 + 8 * g + j) * SX + wave * 16 + n];
#pragma unroll
        for (int mt = 0; mt < 9; ++mt) {
            bf16x8 a = *(const bf16x8*)&w2frag[((mt * 2 + kc2) * 64 + lane) * 8];
            acc2[mt] = __builtin_amdgcn_mfma_f32_16x16x32_bf16(a, hb, acc2[mt], 0, 0, 0);
        }
    }

    // store wk: o2 = mt*16+4g+j, px = wave*16+n
    float* wkb = wk + (size_t)b * KO_ * HW_ + hw0 + wave * 16 + n;
#pragma unroll
    for (int mt = 0; mt < 9; ++mt) {
        const int o0 = mt * 16 + 4 * g;
        float4 bv = *(const float4*)&b2[o0];
        float bj[4] = {bv.x, bv.y, bv.z, bv.w};
#pragma unroll
        for (int j = 0; j < 4; ++j)
            wkb[(size_t)(o0 + j) * HW_] = acc2[mt][j] + bj[j];
    }
}

// ---------------------------------------------------------------------------
// involution, occupancy-doubled: thread = (quad of 4 px, 8 of 16 channels).
// Both channel-halves of a quad live in the SAME block (tid bit 7), so the
// duplicate wk quad-load is an L1 hit on the same CU — no extra HBM bytes.
// Grid 2048 blocks -> 8192 waves -> 32 waves/CU (100% of slots).
// ---------------------------------------------------------------------------
__global__ __launch_bounds__(256) void inv_kernel(const float* __restrict__ x,
                                                  const float* __restrict__ wk,
                                                  float* __restrict__ out) {
    const int Q    = blockIdx.x * 128 + (threadIdx.x & 127);  // quad id
    const int half = threadIdx.x >> 7;                        // 0..1
    const int hw   = (Q & 4095) << 2;
    const int g    = (Q >> 12) & (G_ - 1);
    const int b    = Q >> 16;
    const int h    = hw >> 7;
    const int w0   = hw & (W_ - 1);

    float4 wk4[9];
    const float* wkp = wk + ((size_t)b * KO_ + g * 9) * HW_ + hw;
#pragma unroll
    for (int k = 0; k < 9; ++k) wk4[k] = *(const float4*)&wkp[(size_t)k * HW_];

    const float* xp = x + ((size_t)b * C_ + g * GC_ + half * 8) * HW_ + hw;
    float* op       = out + ((size_t)b * C_ + g * GC_ + half * 8) * HW_ + hw;

    const bool hok0 = (h > 0), hok2 = (h < H_ - 1);
    const bool wl   = (w0 > 0), wr = (w0 < W_ - 4);

#pragma unroll 2
    for (int cc = 0; cc < 8; ++cc) {
        const float* xc = xp + (size_t)cc * HW_;
        float4 acc = {0.f, 0.f, 0.f, 0.f};
#pragma unroll
        for (int r = 0; r < 3; ++r) {
            if ((r == 0 && !hok0) || (r == 2 && !hok2)) continue;
            const float* rp = xc + (r - 1) * W_;
            float4 c = *(const float4*)rp;
            float lm = wl ? rp[-1] : 0.f;
            float rm = wr ? rp[4] : 0.f;
            float4 t0 = wk4[3 * r + 0];
            float4 t1 = wk4[3 * r + 1];
            float4 t2 = wk4[3 * r + 2];
            acc.x = fmaf(t0.x, lm,  acc.x);
            acc.y = fmaf(t0.y, c.x, acc.y);
            acc.z = fmaf(t0.z, c.y, acc.z);
            acc.w = fmaf(t0.w, c.z, acc.w);
            acc.x = fmaf(t1.x, c.x, acc.x);
            acc.y = fmaf(t1.y, c.y, acc.y);
            acc.z = fmaf(t1.z, c.z, acc.z);
            acc.w = fmaf(t1.w, c.w, acc.w);
            acc.x = fmaf(t2.x, c.y, acc.x);
            acc.y = fmaf(t2.y, c.z, acc.y);
            acc.z = fmaf(t2.z, c.w, acc.z);
            acc.w = fmaf(t2.w, rm,  acc.w);
        }
        *(float4*)&op[(size_t)cc * HW_] = acc;
    }
}

// ---------------------------------------------------------------------------
extern "C" void kernel_launch(void* const* d_in, const int* in_sizes, int n_in,
                              void* d_out, int out_size, void* d_ws, size_t ws_size,
                              hipStream_t stream) {
    const float* x     = (const float*)d_in[0];
    const float* w1    = (const float*)d_in[1];
    const float* gamma = (const float*)d_in[2];
    const float* beta  = (const float*)d_in[3];
    const float* mean  = (const float*)d_in[4];
    const float* var   = (const float*)d_in[5];
    const float* w2    = (const float*)d_in[6];
    const float* b2    = (const float*)d_in[7];
    float* out = (float*)d_out;

    char* ws = (char*)d_ws;
    __bf16* w1frag = (__bf16*)(ws);                 // 32 KB [8][4][64][8]
    __bf16* w2frag = (__bf16*)(ws + (32 << 10));    // 18 KB [9][2][64][8]
    float*  bias2  = (float*)(ws + (56 << 10));     // 256 B
    float*  wkbuf  = (float*)(ws + (1 << 20));      // 36 MB [B][144][HW]

    hipLaunchKernelGGL(prep_kernel, dim3(100), dim3(256), 0, stream,
                       w1, gamma, beta, mean, var, w2, w1frag, w2frag, bias2);
    hipLaunchKernelGGL(conv12_kernel, dim3(1024), dim3(256), 0, stream,
                       x, w1frag, bias2, w2frag, b2, wkbuf);
    hipLaunchKernelGGL(inv_kernel, dim3(2048), dim3(256), 0, stream,
                       x, wkbuf, out);
}

// Round 12
// 67.902 us; speedup vs baseline: 1.1226x; 1.0318x over previous
//
#include <hip/hip_runtime.h>

#define B_   4
#define C_   256
#define CR_  64
#define H_   128
#define W_   128
#define HW_  (H_ * W_)
#define G_   16
#define GC_  16
#define KO_  144   // K*K*G = 9*16
#define EPS_ 1e-5f

typedef __bf16 bf16x8 __attribute__((ext_vector_type(8)));
typedef __bf16 bf16x4 __attribute__((ext_vector_type(4)));
typedef __bf16 bf16x2 __attribute__((ext_vector_type(2)));
typedef float  f32x4  __attribute__((ext_vector_type(4)));

#define SX 66   // LDS row stride (elements) for xs/hbuf: banks 2-way on gathers

// ---------------------------------------------------------------------------
// prep: build MFMA A-fragments (lane order: m = lane&15, kslot = 8*(lane>>4)+j;
// the kslot permutation cancels between A and B since both use it).
// ---------------------------------------------------------------------------
__global__ void prep_kernel(const float* __restrict__ w1,
                            const float* __restrict__ gamma,
                            const float* __restrict__ beta,
                            const float* __restrict__ mean,
                            const float* __restrict__ var,
                            const float* __restrict__ w2,
                            __bf16* __restrict__ w1frag,
                            __bf16* __restrict__ w2frag,
                            float* __restrict__ bias2) {
    int idx = blockIdx.x * 256 + threadIdx.x;
    if (idx < 16384) {                      // w1frag: [8 kc][4 mt][64 l][8 j]
        int kc = idx >> 11, r = idx & 2047;
        int mt = r >> 9, l = (r >> 3) & 63, j = r & 7;
        int o = mt * 16 + (l & 15);
        int c = kc * 32 + 8 * (l >> 4) + j;
        float alpha = gamma[o] * rsqrtf(var[o] + EPS_);
        w1frag[idx] = (__bf16)(w1[o * C_ + c] * alpha);
        if (idx < CR_) {
            float a2 = gamma[idx] * rsqrtf(var[idx] + EPS_);
            bias2[idx] = beta[idx] - mean[idx] * a2;
        }
    } else if (idx < 16384 + 9216) {        // w2frag: [9 mt][2 kc2][64 l][8 j]
        int i2 = idx - 16384;
        int mt = i2 >> 10, r = i2 & 1023;
        int kc2 = r >> 9, l = (r >> 3) & 63, j = r & 7;
        int o2 = mt * 16 + (l & 15);
        int cc = kc2 * 32 + 8 * (l >> 4) + j;
        w2frag[i2] = (__bf16)(w2[o2 * CR_ + cc]);
    }
}

// ---------------------------------------------------------------------------
// fused conv1(+BN+ReLU) + conv2 via bf16 MFMA, fp32 accumulate.
// wk now stored as bf16 (halves WRITE traffic; wk is bf16-limited anyway).
// ---------------------------------------------------------------------------
__global__ __launch_bounds__(256, 4) void conv12_kernel(
        const float* __restrict__ x,
        const __bf16* __restrict__ w1frag,
        const float* __restrict__ bias2,
        const __bf16* __restrict__ w2frag,
        const float* __restrict__ b2,
        __bf16* __restrict__ wk) {
    __shared__ __bf16 xs[2 * 32 * SX];     // 8.4 KB double-buffered x chunk
    __shared__ __bf16 hbuf[CR_ * SX];      // 8.4 KB h tile (bf16)

    const int tid  = threadIdx.x;
    const int lane = tid & 63;
    const int wave = tid >> 6;
    const int wm = wave >> 1, wn = wave & 1;
    const int g = lane >> 4, n = lane & 15;

    const int px0 = blockIdx.x * 64;
    const int b   = px0 >> 14;
    const int hw0 = px0 & (HW_ - 1);

    const float* xb = x + (size_t)b * C_ * HW_ + hw0;
    const int krow = tid >> 3;             // 0..31 (k row within chunk)
    const int t8   = tid & 7;              // 0..7

    // ---- stage chunk 0 into buf 0 ----
    {
        float4 v0 = *(const float4*)&xb[(size_t)krow * HW_ + 4 * t8];
        float4 v1 = *(const float4*)&xb[(size_t)krow * HW_ + 32 + 4 * t8];
        __bf16* d0 = &xs[krow * SX + 4 * t8];
        __bf16* d1 = &xs[krow * SX + 32 + 4 * t8];
        *(bf16x2*)&d0[0] = bf16x2{(__bf16)v0.x, (__bf16)v0.y};
        *(bf16x2*)&d0[2] = bf16x2{(__bf16)v0.z, (__bf16)v0.w};
        *(bf16x2*)&d1[0] = bf16x2{(__bf16)v1.x, (__bf16)v1.y};
        *(bf16x2*)&d1[2] = bf16x2{(__bf16)v1.z, (__bf16)v1.w};
    }
    __syncthreads();

    // ======================= phase 1 ============================
    f32x4 acc1[2][2];
#pragma unroll
    for (int m = 0; m < 2; ++m)
#pragma unroll
        for (int t = 0; t < 2; ++t) acc1[m][t] = f32x4{0.f, 0.f, 0.f, 0.f};

    for (int kc = 0; kc < 8; ++kc) {
        const int buf = kc & 1;
        float4 nf0, nf1;
        if (kc < 7) {   // issue next chunk's loads early (hide HBM latency)
            nf0 = *(const float4*)&xb[(size_t)(32 * (kc + 1) + krow) * HW_ + 4 * t8];
            nf1 = *(const float4*)&xb[(size_t)(32 * (kc + 1) + krow) * HW_ + 32 + 4 * t8];
        }
        bf16x8 a0 = *(const bf16x8*)&w1frag[((kc * 4 + 2 * wm + 0) * 64 + lane) * 8];
        bf16x8 a1 = *(const bf16x8*)&w1frag[((kc * 4 + 2 * wm + 1) * 64 + lane) * 8];
        const int base = buf * (32 * SX);
        bf16x8 b0, b1;
#pragma unroll
        for (int j = 0; j < 8; ++j) {
            b0[j] = xs[base + (8 * g + j) * SX + (2 * wn + 0) * 16 + n];
            b1[j] = xs[base + (8 * g + j) * SX + (2 * wn + 1) * 16 + n];
        }
        acc1[0][0] = __builtin_amdgcn_mfma_f32_16x16x32_bf16(a0, b0, acc1[0][0], 0, 0, 0);
        acc1[0][1] = __builtin_amdgcn_mfma_f32_16x16x32_bf16(a0, b1, acc1[0][1], 0, 0, 0);
        acc1[1][0] = __builtin_amdgcn_mfma_f32_16x16x32_bf16(a1, b0, acc1[1][0], 0, 0, 0);
        acc1[1][1] = __builtin_amdgcn_mfma_f32_16x16x32_bf16(a1, b1, acc1[1][1], 0, 0, 0);

        if (kc < 7) {
            __bf16* d0 = &xs[(buf ^ 1) * (32 * SX) + krow * SX + 4 * t8];
            __bf16* d1 = &xs[(buf ^ 1) * (32 * SX) + krow * SX + 32 + 4 * t8];
            *(bf16x2*)&d0[0] = bf16x2{(__bf16)nf0.x, (__bf16)nf0.y};
            *(bf16x2*)&d0[2] = bf16x2{(__bf16)nf0.z, (__bf16)nf0.w};
            *(bf16x2*)&d1[0] = bf16x2{(__bf16)nf1.x, (__bf16)nf1.y};
            *(bf16x2*)&d1[2] = bf16x2{(__bf16)nf1.z, (__bf16)nf1.w};
        }
        __syncthreads();
    }

    // bias + relu -> hbuf (bf16). D elem: o = Mt*16+4g+j, px = Nt*16+n
#pragma unroll
    for (int m = 0; m < 2; ++m) {
        const int Mo = (2 * wm + m) * 16 + 4 * g;
        float4 bv = *(const float4*)&bias2[Mo];
        float bj[4] = {bv.x, bv.y, bv.z, bv.w};
#pragma unroll
        for (int t = 0; t < 2; ++t) {
            const int px = (2 * wn + t) * 16 + n;
#pragma unroll
            for (int j = 0; j < 4; ++j) {
                hbuf[(Mo + j) * SX + px] = (__bf16)fmaxf(acc1[m][t][j] + bj[j], 0.f);
            }
        }
    }
    __syncthreads();

    // ======================= phase 2 ============================
    f32x4 acc2[9];
#pragma unroll
    for (int m = 0; m < 9; ++m) acc2[m] = f32x4{0.f, 0.f, 0.f, 0.f};

#pragma unroll
    for (int kc2 = 0; kc2 < 2; ++kc2) {
        bf16x8 hb;
#pragma unroll
        for (int j = 0; j < 8; ++j)
            hb[j] = hbuf[(kc2 * 32 + 8 * g + j) * SX + wave * 16 + n];
#pragma unroll
        for (int mt = 0; mt < 9; ++mt) {
            bf16x8 a = *(const bf16x8*)&w2frag[((mt * 2 + kc2) * 64 + lane) * 8];
            acc2[mt] = __builtin_amdgcn_mfma_f32_16x16x32_bf16(a, hb, acc2[mt], 0, 0, 0);
        }
    }

    // store wk (bf16): o2 = mt*16+4g+j, px = wave*16+n
    __bf16* wkb = wk + (size_t)b * KO_ * HW_ + hw0 + wave * 16 + n;
#pragma unroll
    for (int mt = 0; mt < 9; ++mt) {
        const int o0 = mt * 16 + 4 * g;
        float4 bv = *(const float4*)&b2[o0];
        float bj[4] = {bv.x, bv.y, bv.z, bv.w};
#pragma unroll
        for (int j = 0; j < 4; ++j)
            wkb[(size_t)(o0 + j) * HW_] = (__bf16)(acc2[mt][j] + bj[j]);
    }
}

// ---------------------------------------------------------------------------
// involution: thread = (quad of 4 px, 8 of 16 channels), grid 2048.
// 2-deep software pipeline over channels: rows for ch cc+1 issued while
// computing ch cc. Absent rows are exact zeros (fmaf(t,0,acc)==acc), so the
// body is branch-free and fully unrolled -> ~10 loads in flight.
// ---------------------------------------------------------------------------
__global__ __launch_bounds__(256) void inv_kernel(const float* __restrict__ x,
                                                  const __bf16* __restrict__ wkb,
                                                  float* __restrict__ out) {
    const int Q    = blockIdx.x * 128 + (threadIdx.x & 127);  // quad id
    const int half = threadIdx.x >> 7;                        // 0..1
    const int hw   = (Q & 4095) << 2;
    const int g    = (Q >> 12) & (G_ - 1);
    const int b    = Q >> 16;
    const int h    = hw >> 7;
    const int w0   = hw & (W_ - 1);

    float4 wk4[9];
    const __bf16* wkp = wkb + ((size_t)b * KO_ + g * 9) * HW_ + hw;
#pragma unroll
    for (int k = 0; k < 9; ++k) {
        bf16x4 v = *(const bf16x4*)&wkp[(size_t)k * HW_];
        wk4[k] = float4{(float)v[0], (float)v[1], (float)v[2], (float)v[3]};
    }

    const float* xp = x + ((size_t)b * C_ + g * GC_ + half * 8) * HW_ + hw;
    float* op       = out + ((size_t)b * C_ + g * GC_ + half * 8) * HW_ + hw;

    const bool hok0 = (h > 0), hok2 = (h < H_ - 1);
    const bool wl   = (w0 > 0), wr = (w0 < W_ - 4);

    auto LOADCH = [&](int cc, float4* c, float* le, float* re) {
        const float* xc = xp + (size_t)cc * HW_;
#pragma unroll
        for (int r = 0; r < 3; ++r) {
            const bool ok = (r == 0) ? hok0 : (r == 2) ? hok2 : true;
            const float* rp = xc + (r - 1) * W_;
            if (ok) {
                c[r]  = *(const float4*)rp;
                le[r] = wl ? rp[-1] : 0.f;
                re[r] = wr ? rp[4] : 0.f;
            } else {
                c[r]  = float4{0.f, 0.f, 0.f, 0.f};
                le[r] = 0.f;
                re[r] = 0.f;
            }
        }
    };
    auto COMPUTE = [&](int cc, const float4* c, const float* le, const float* re) {
        float4 acc = {0.f, 0.f, 0.f, 0.f};
#pragma unroll
        for (int r = 0; r < 3; ++r) {
            float4 t0 = wk4[3 * r + 0];
            float4 t1 = wk4[3 * r + 1];
            float4 t2 = wk4[3 * r + 2];
            acc.x = fmaf(t0.x, le[r],  acc.x);
            acc.y = fmaf(t0.y, c[r].x, acc.y);
            acc.z = fmaf(t0.z, c[r].y, acc.z);
            acc.w = fmaf(t0.w, c[r].z, acc.w);
            acc.x = fmaf(t1.x, c[r].x, acc.x);
            acc.y = fmaf(t1.y, c[r].y, acc.y);
            acc.z = fmaf(t1.z, c[r].z, acc.z);
            acc.w = fmaf(t1.w, c[r].w, acc.w);
            acc.x = fmaf(t2.x, c[r].y, acc.x);
            acc.y = fmaf(t2.y, c[r].z, acc.y);
            acc.z = fmaf(t2.z, c[r].w, acc.z);
            acc.w = fmaf(t2.w, re[r],  acc.w);
        }
        *(float4*)&op[(size_t)cc * HW_] = acc;
    };

    float4 ca[3], cb[3];
    float  la[3], ra[3], lb[3], rb[3];
    LOADCH(0, ca, la, ra);
#pragma unroll
    for (int cc = 0; cc < 8; ++cc) {
        if ((cc & 1) == 0) {
            if (cc < 7) LOADCH(cc + 1, cb, lb, rb);
            COMPUTE(cc, ca, la, ra);
        } else {
            if (cc < 7) LOADCH(cc + 1, ca, la, ra);
            COMPUTE(cc, cb, lb, rb);
        }
    }
}

// ---------------------------------------------------------------------------
extern "C" void kernel_launch(void* const* d_in, const int* in_sizes, int n_in,
                              void* d_out, int out_size, void* d_ws, size_t ws_size,
                              hipStream_t stream) {
    const float* x     = (const float*)d_in[0];
    const float* w1    = (const float*)d_in[1];
    const float* gamma = (const float*)d_in[2];
    const float* beta  = (const float*)d_in[3];
    const float* mean  = (const float*)d_in[4];
    const float* var   = (const float*)d_in[5];
    const float* w2    = (const float*)d_in[6];
    const float* b2    = (const float*)d_in[7];
    float* out = (float*)d_out;

    char* ws = (char*)d_ws;
    __bf16* w1frag = (__bf16*)(ws);                 // 32 KB [8][4][64][8]
    __bf16* w2frag = (__bf16*)(ws + (32 << 10));    // 18 KB [9][2][64][8]
    float*  bias2  = (float*)(ws + (56 << 10));     // 256 B
    __bf16* wkbuf  = (__bf16*)(ws + (1 << 20));     // 18 MB [B][144][HW] bf16

    hipLaunchKernelGGL(prep_kernel, dim3(100), dim3(256), 0, stream,
                       w1, gamma, beta, mean, var, w2, w1frag, w2frag, bias2);
    hipLaunchKernelGGL(conv12_kernel, dim3(1024), dim3(256), 0, stream,
                       x, w1frag, bias2, w2frag, b2, wkbuf);
    hipLaunchKernelGGL(inv_kernel, dim3(2048), dim3(256), 0, stream,
                       x, wkbuf, out);
}

// Round 13
// 64.318 us; speedup vs baseline: 1.1852x; 1.0557x over previous
//
#include <hip/hip_runtime.h>

#define B_   4
#define C_   256
#define CR_  64
#define H_   128
#define W_   128
#define HW_  (H_ * W_)
#define G_   16
#define GC_  16
#define KO_  144   // K*K*G = 9*16
#define EPS_ 1e-5f

typedef __bf16 bf16x8 __attribute__((ext_vector_type(8)));
typedef __bf16 bf16x4 __attribute__((ext_vector_type(4)));
typedef __bf16 bf16x2 __attribute__((ext_vector_type(2)));
typedef float  f32x4  __attribute__((ext_vector_type(4)));

#define SX 66   // LDS row stride (elements) for xs/hbuf: banks 2-way on gathers

// ---------------------------------------------------------------------------
// prep: build MFMA A-fragments (lane order: m = lane&15, kslot = 8*(lane>>4)+j;
// the kslot permutation cancels between A and B since both use it).
// ---------------------------------------------------------------------------
__global__ void prep_kernel(const float* __restrict__ w1,
                            const float* __restrict__ gamma,
                            const float* __restrict__ beta,
                            const float* __restrict__ mean,
                            const float* __restrict__ var,
                            const float* __restrict__ w2,
                            __bf16* __restrict__ w1frag,
                            __bf16* __restrict__ w2frag,
                            float* __restrict__ bias2) {
    int idx = blockIdx.x * 256 + threadIdx.x;
    if (idx < 16384) {                      // w1frag: [8 kc][4 mt][64 l][8 j]
        int kc = idx >> 11, r = idx & 2047;
        int mt = r >> 9, l = (r >> 3) & 63, j = r & 7;
        int o = mt * 16 + (l & 15);
        int c = kc * 32 + 8 * (l >> 4) + j;
        float alpha = gamma[o] * rsqrtf(var[o] + EPS_);
        w1frag[idx] = (__bf16)(w1[o * C_ + c] * alpha);
        if (idx < CR_) {
            float a2 = gamma[idx] * rsqrtf(var[idx] + EPS_);
            bias2[idx] = beta[idx] - mean[idx] * a2;
        }
    } else if (idx < 16384 + 9216) {        // w2frag: [9 mt][2 kc2][64 l][8 j]
        int i2 = idx - 16384;
        int mt = i2 >> 10, r = i2 & 1023;
        int kc2 = r >> 9, l = (r >> 3) & 63, j = r & 7;
        int o2 = mt * 16 + (l & 15);
        int cc = kc2 * 32 + 8 * (l >> 4) + j;
        w2frag[i2] = (__bf16)(w2[o2 * CR_ + cc]);
    }
}

// ---------------------------------------------------------------------------
// fused conv1(+BN+ReLU) + conv2 via bf16 MFMA, fp32 accumulate.
// wk stored as bf16. (unchanged from R8 — ~21 us)
// ---------------------------------------------------------------------------
__global__ __launch_bounds__(256, 4) void conv12_kernel(
        const float* __restrict__ x,
        const __bf16* __restrict__ w1frag,
        const float* __restrict__ bias2,
        const __bf16* __restrict__ w2frag,
        const float* __restrict__ b2,
        __bf16* __restrict__ wk) {
    __shared__ __bf16 xs[2 * 32 * SX];     // 8.4 KB double-buffered x chunk
    __shared__ __bf16 hbuf[CR_ * SX];      // 8.4 KB h tile (bf16)

    const int tid  = threadIdx.x;
    const int lane = tid & 63;
    const int wave = tid >> 6;
    const int wm = wave >> 1, wn = wave & 1;
    const int g = lane >> 4, n = lane & 15;

    const int px0 = blockIdx.x * 64;
    const int b   = px0 >> 14;
    const int hw0 = px0 & (HW_ - 1);

    const float* xb = x + (size_t)b * C_ * HW_ + hw0;
    const int krow = tid >> 3;             // 0..31 (k row within chunk)
    const int t8   = tid & 7;              // 0..7

    // ---- stage chunk 0 into buf 0 ----
    {
        float4 v0 = *(const float4*)&xb[(size_t)krow * HW_ + 4 * t8];
        float4 v1 = *(const float4*)&xb[(size_t)krow * HW_ + 32 + 4 * t8];
        __bf16* d0 = &xs[krow * SX + 4 * t8];
        __bf16* d1 = &xs[krow * SX + 32 + 4 * t8];
        *(bf16x2*)&d0[0] = bf16x2{(__bf16)v0.x, (__bf16)v0.y};
        *(bf16x2*)&d0[2] = bf16x2{(__bf16)v0.z, (__bf16)v0.w};
        *(bf16x2*)&d1[0] = bf16x2{(__bf16)v1.x, (__bf16)v1.y};
        *(bf16x2*)&d1[2] = bf16x2{(__bf16)v1.z, (__bf16)v1.w};
    }
    __syncthreads();

    // ======================= phase 1 ============================
    f32x4 acc1[2][2];
#pragma unroll
    for (int m = 0; m < 2; ++m)
#pragma unroll
        for (int t = 0; t < 2; ++t) acc1[m][t] = f32x4{0.f, 0.f, 0.f, 0.f};

    for (int kc = 0; kc < 8; ++kc) {
        const int buf = kc & 1;
        float4 nf0, nf1;
        if (kc < 7) {   // issue next chunk's loads early (hide HBM latency)
            nf0 = *(const float4*)&xb[(size_t)(32 * (kc + 1) + krow) * HW_ + 4 * t8];
            nf1 = *(const float4*)&xb[(size_t)(32 * (kc + 1) + krow) * HW_ + 32 + 4 * t8];
        }
        bf16x8 a0 = *(const bf16x8*)&w1frag[((kc * 4 + 2 * wm + 0) * 64 + lane) * 8];
        bf16x8 a1 = *(const bf16x8*)&w1frag[((kc * 4 + 2 * wm + 1) * 64 + lane) * 8];
        const int base = buf * (32 * SX);
        bf16x8 b0, b1;
#pragma unroll
        for (int j = 0; j < 8; ++j) {
            b0[j] = xs[base + (8 * g + j) * SX + (2 * wn + 0) * 16 + n];
            b1[j] = xs[base + (8 * g + j) * SX + (2 * wn + 1) * 16 + n];
        }
        acc1[0][0] = __builtin_amdgcn_mfma_f32_16x16x32_bf16(a0, b0, acc1[0][0], 0, 0, 0);
        acc1[0][1] = __builtin_amdgcn_mfma_f32_16x16x32_bf16(a0, b1, acc1[0][1], 0, 0, 0);
        acc1[1][0] = __builtin_amdgcn_mfma_f32_16x16x32_bf16(a1, b0, acc1[1][0], 0, 0, 0);
        acc1[1][1] = __builtin_amdgcn_mfma_f32_16x16x32_bf16(a1, b1, acc1[1][1], 0, 0, 0);

        if (kc < 7) {
            __bf16* d0 = &xs[(buf ^ 1) * (32 * SX) + krow * SX + 4 * t8];
            __bf16* d1 = &xs[(buf ^ 1) * (32 * SX) + krow * SX + 32 + 4 * t8];
            *(bf16x2*)&d0[0] = bf16x2{(__bf16)nf0.x, (__bf16)nf0.y};
            *(bf16x2*)&d0[2] = bf16x2{(__bf16)nf0.z, (__bf16)nf0.w};
            *(bf16x2*)&d1[0] = bf16x2{(__bf16)nf1.x, (__bf16)nf1.y};
            *(bf16x2*)&d1[2] = bf16x2{(__bf16)nf1.z, (__bf16)nf1.w};
        }
        __syncthreads();
    }

    // bias + relu -> hbuf (bf16). D elem: o = Mt*16+4g+j, px = Nt*16+n
#pragma unroll
    for (int m = 0; m < 2; ++m) {
        const int Mo = (2 * wm + m) * 16 + 4 * g;
        float4 bv = *(const float4*)&bias2[Mo];
        float bj[4] = {bv.x, bv.y, bv.z, bv.w};
#pragma unroll
        for (int t = 0; t < 2; ++t) {
            const int px = (2 * wn + t) * 16 + n;
#pragma unroll
            for (int j = 0; j < 4; ++j) {
                hbuf[(Mo + j) * SX + px] = (__bf16)fmaxf(acc1[m][t][j] + bj[j], 0.f);
            }
        }
    }
    __syncthreads();

    // ======================= phase 2 ============================
    f32x4 acc2[9];
#pragma unroll
    for (int m = 0; m < 9; ++m) acc2[m] = f32x4{0.f, 0.f, 0.f, 0.f};

#pragma unroll
    for (int kc2 = 0; kc2 < 2; ++kc2) {
        bf16x8 hb;
#pragma unroll
        for (int j = 0; j < 8; ++j)
            hb[j] = hbuf[(kc2 * 32 + 8 * g + j) * SX + wave * 16 + n];
#pragma unroll
        for (int mt = 0; mt < 9; ++mt) {
            bf16x8 a = *(const bf16x8*)&w2frag[((mt * 2 + kc2) * 64 + lane) * 8];
            acc2[mt] = __builtin_amdgcn_mfma_f32_16x16x32_bf16(a, hb, acc2[mt], 0, 0, 0);
        }
    }

    // store wk (bf16): o2 = mt*16+4g+j, px = wave*16+n
    __bf16* wkb = wk + (size_t)b * KO_ * HW_ + hw0 + wave * 16 + n;
#pragma unroll
    for (int mt = 0; mt < 9; ++mt) {
        const int o0 = mt * 16 + 4 * g;
        float4 bv = *(const float4*)&b2[o0];
        float bj[4] = {bv.x, bv.y, bv.z, bv.w};
#pragma unroll
        for (int j = 0; j < 4; ++j)
            wkb[(size_t)(o0 + j) * HW_] = (__bf16)(acc2[mt][j] + bj[j]);
    }
}

// ---------------------------------------------------------------------------
// involution via LDS-staged x window.
// Block = (b, g, 4-row x 128-col tile). Stage 16ch x 6rows x 128px fp32 into
// LDS with coalesced dwordx4 (each global line touched ~1.5x, vs ~10x when
// tapping global directly). Taps read from LDS: b128 + 2x b32 per row.
// W-edges and H-edges are ZERO PADS in LDS -> branch-free FMA body.
// Row stride 132: cols 0..127 data, 128..131 zeros; +4 front guard.
// Thread = (half, row, quad): 8 channels x 1 row-quad = 32 outputs.
// ---------------------------------------------------------------------------
__global__ __launch_bounds__(256, 3) void inv_kernel(const float* __restrict__ x,
                                                     const __bf16* __restrict__ wkb,
                                                     float* __restrict__ out) {
    __shared__ float lds[4 + 96 * 132];              // 50704 B
    const int bi   = blockIdx.x;
    const int tile = bi & 31;
    const int g    = (bi >> 5) & 15;
    const int b    = bi >> 9;
    const int h0   = tile * 4;
    const int tid  = threadIdx.x;

    // ---- stage x window: rows h0-1 .. h0+4, 16 channels, zero H-edges ----
    const float* xg = x + ((size_t)b * C_ + g * GC_) * HW_;
#pragma unroll
    for (int i = 0; i < 12; ++i) {
        int s = tid + 256 * i;                       // 0..3071
        int chrow = s >> 5, f4 = s & 31;
        int ch = chrow / 6, row = chrow - 6 * ch;
        int gh = h0 - 1 + row;
        float4 v = {0.f, 0.f, 0.f, 0.f};
        if (gh >= 0 && gh < H_)
            v = *(const float4*)&xg[((size_t)ch * H_ + gh) * W_ + f4 * 4];
        *(float4*)&lds[4 + chrow * 132 + f4 * 4] = v;
    }
    if (tid < 96)  *(float4*)&lds[4 + tid * 132 + 128] = float4{0.f, 0.f, 0.f, 0.f};
    if (tid == 96) *(float4*)&lds[0] = float4{0.f, 0.f, 0.f, 0.f};
    __syncthreads();

    // ---- compute: thread = (half=tid>>7, row=(tid>>5)&3, quad=tid&31) ----
    const int q    = tid & 31;
    const int row  = (tid >> 5) & 3;
    const int half = tid >> 7;
    const int w0   = q * 4;
    const int hh   = h0 + row;

    // wk: 9 taps for this row-quad (bf16 -> fp32), reused over 8 channels
    float4 wk4[9];
    const __bf16* wkp = wkb + ((size_t)b * KO_ + g * 9) * HW_ + hh * W_ + w0;
#pragma unroll
    for (int k = 0; k < 9; ++k) {
        bf16x4 v = *(const bf16x4*)&wkp[(size_t)k * HW_];
        wk4[k] = float4{(float)v[0], (float)v[1], (float)v[2], (float)v[3]};
    }

    float* op = out + ((size_t)b * C_ + g * GC_ + half * 8) * HW_ + hh * W_ + w0;

#pragma unroll
    for (int cc = 0; cc < 8; ++cc) {
        const int ch = half * 8 + cc;
        const float* base = &lds[4 + (ch * 6 + row) * 132 + w0];
        float4 acc = {0.f, 0.f, 0.f, 0.f};
#pragma unroll
        for (int dr = 0; dr < 3; ++dr) {
            const float* rp = base + dr * 132;
            float4 c = *(const float4*)rp;           // ds_read_b128
            float lm = rp[-1];                       // zero-pad / guard at edges
            float rm = rp[4];                        // zero-pad at w0=124
            float4 t0 = wk4[3 * dr + 0];
            float4 t1 = wk4[3 * dr + 1];
            float4 t2 = wk4[3 * dr + 2];
            acc.x = fmaf(t0.x, lm,  acc.x);
            acc.y = fmaf(t0.y, c.x, acc.y);
            acc.z = fmaf(t0.z, c.y, acc.z);
            acc.w = fmaf(t0.w, c.z, acc.w);
            acc.x = fmaf(t1.x, c.x, acc.x);
            acc.y = fmaf(t1.y, c.y, acc.y);
            acc.z = fmaf(t1.z, c.z, acc.z);
            acc.w = fmaf(t1.w, c.w, acc.w);
            acc.x = fmaf(t2.x, c.y, acc.x);
            acc.y = fmaf(t2.y, c.z, acc.y);
            acc.z = fmaf(t2.z, c.w, acc.z);
            acc.w = fmaf(t2.w, rm,  acc.w);
        }
        *(float4*)&op[(size_t)cc * HW_] = acc;
    }
}

// ---------------------------------------------------------------------------
extern "C" void kernel_launch(void* const* d_in, const int* in_sizes, int n_in,
                              void* d_out, int out_size, void* d_ws, size_t ws_size,
                              hipStream_t stream) {
    const float* x     = (const float*)d_in[0];
    const float* w1    = (const float*)d_in[1];
    const float* gamma = (const float*)d_in[2];
    const float* beta  = (const float*)d_in[3];
    const float* mean  = (const float*)d_in[4];
    const float* var   = (const float*)d_in[5];
    const float* w2    = (const float*)d_in[6];
    const float* b2    = (const float*)d_in[7];
    float* out = (float*)d_out;

    char* ws = (char*)d_ws;
    __bf16* w1frag = (__bf16*)(ws);                 // 32 KB [8][4][64][8]
    __bf16* w2frag = (__bf16*)(ws + (32 << 10));    // 18 KB [9][2][64][8]
    float*  bias2  = (float*)(ws + (56 << 10));     // 256 B
    __bf16* wkbuf  = (__bf16*)(ws + (1 << 20));     // 18 MB [B][144][HW] bf16

    hipLaunchKernelGGL(prep_kernel, dim3(100), dim3(256), 0, stream,
                       w1, gamma, beta, mean, var, w2, w1frag, w2frag, bias2);
    hipLaunchKernelGGL(conv12_kernel, dim3(1024), dim3(256), 0, stream,
                       x, w1frag, bias2, w2frag, b2, wkbuf);
    hipLaunchKernelGGL(inv_kernel, dim3(2048), dim3(256), 0, stream,
                       x, wkbuf, out);
}

// Round 14
// 58.069 us; speedup vs baseline: 1.3127x; 1.1076x over previous
//
#include <hip/hip_runtime.h>

#define B_   4
#define C_   256
#define CR_  64
#define H_   128
#define W_   128
#define HW_  (H_ * W_)
#define G_   16
#define GC_  16
#define KO_  144   // K*K*G = 9*16
#define EPS_ 1e-5f

typedef __bf16 bf16x8 __attribute__((ext_vector_type(8)));
typedef __bf16 bf16x4 __attribute__((ext_vector_type(4)));
typedef __bf16 bf16x2 __attribute__((ext_vector_type(2)));
typedef float  f32x4  __attribute__((ext_vector_type(4)));

#define SX 66   // LDS row stride (elements) for xs/hbuf: banks 2-way on gathers

// ---------------------------------------------------------------------------
// prep: build MFMA A-fragments (lane order: m = lane&15, kslot = 8*(lane>>4)+j;
// the kslot permutation cancels between A and B since both use it).
// ---------------------------------------------------------------------------
__global__ void prep_kernel(const float* __restrict__ w1,
                            const float* __restrict__ gamma,
                            const float* __restrict__ beta,
                            const float* __restrict__ mean,
                            const float* __restrict__ var,
                            const float* __restrict__ w2,
                            __bf16* __restrict__ w1frag,
                            __bf16* __restrict__ w2frag,
                            float* __restrict__ bias2) {
    int idx = blockIdx.x * 256 + threadIdx.x;
    if (idx < 16384) {                      // w1frag: [8 kc][4 mt][64 l][8 j]
        int kc = idx >> 11, r = idx & 2047;
        int mt = r >> 9, l = (r >> 3) & 63, j = r & 7;
        int o = mt * 16 + (l & 15);
        int c = kc * 32 + 8 * (l >> 4) + j;
        float alpha = gamma[o] * rsqrtf(var[o] + EPS_);
        w1frag[idx] = (__bf16)(w1[o * C_ + c] * alpha);
        if (idx < CR_) {
            float a2 = gamma[idx] * rsqrtf(var[idx] + EPS_);
            bias2[idx] = beta[idx] - mean[idx] * a2;
        }
    } else if (idx < 16384 + 9216) {        // w2frag: [9 mt][2 kc2][64 l][8 j]
        int i2 = idx - 16384;
        int mt = i2 >> 10, r = i2 & 1023;
        int kc2 = r >> 9, l = (r >> 3) & 63, j = r & 7;
        int o2 = mt * 16 + (l & 15);
        int cc = kc2 * 32 + 8 * (l >> 4) + j;
        w2frag[i2] = (__bf16)(w2[o2 * CR_ + cc]);
    }
}

// ---------------------------------------------------------------------------
// fused conv1(+BN+ReLU) + conv2 via bf16 MFMA, fp32 accumulate.
// wk stored as bf16. (unchanged from R8/R9 — ~21 us)
// ---------------------------------------------------------------------------
__global__ __launch_bounds__(256, 4) void conv12_kernel(
        const float* __restrict__ x,
        const __bf16* __restrict__ w1frag,
        const float* __restrict__ bias2,
        const __bf16* __restrict__ w2frag,
        const float* __restrict__ b2,
        __bf16* __restrict__ wk) {
    __shared__ __bf16 xs[2 * 32 * SX];     // 8.4 KB double-buffered x chunk
    __shared__ __bf16 hbuf[CR_ * SX];      // 8.4 KB h tile (bf16)

    const int tid  = threadIdx.x;
    const int lane = tid & 63;
    const int wave = tid >> 6;
    const int wm = wave >> 1, wn = wave & 1;
    const int g = lane >> 4, n = lane & 15;

    const int px0 = blockIdx.x * 64;
    const int b   = px0 >> 14;
    const int hw0 = px0 & (HW_ - 1);

    const float* xb = x + (size_t)b * C_ * HW_ + hw0;
    const int krow = tid >> 3;             // 0..31 (k row within chunk)
    const int t8   = tid & 7;              // 0..7

    // ---- stage chunk 0 into buf 0 ----
    {
        float4 v0 = *(const float4*)&xb[(size_t)krow * HW_ + 4 * t8];
        float4 v1 = *(const float4*)&xb[(size_t)krow * HW_ + 32 + 4 * t8];
        __bf16* d0 = &xs[krow * SX + 4 * t8];
        __bf16* d1 = &xs[krow * SX + 32 + 4 * t8];
        *(bf16x2*)&d0[0] = bf16x2{(__bf16)v0.x, (__bf16)v0.y};
        *(bf16x2*)&d0[2] = bf16x2{(__bf16)v0.z, (__bf16)v0.w};
        *(bf16x2*)&d1[0] = bf16x2{(__bf16)v1.x, (__bf16)v1.y};
        *(bf16x2*)&d1[2] = bf16x2{(__bf16)v1.z, (__bf16)v1.w};
    }
    __syncthreads();

    // ======================= phase 1 ============================
    f32x4 acc1[2][2];
#pragma unroll
    for (int m = 0; m < 2; ++m)
#pragma unroll
        for (int t = 0; t < 2; ++t) acc1[m][t] = f32x4{0.f, 0.f, 0.f, 0.f};

    for (int kc = 0; kc < 8; ++kc) {
        const int buf = kc & 1;
        float4 nf0, nf1;
        if (kc < 7) {   // issue next chunk's loads early (hide HBM latency)
            nf0 = *(const float4*)&xb[(size_t)(32 * (kc + 1) + krow) * HW_ + 4 * t8];
            nf1 = *(const float4*)&xb[(size_t)(32 * (kc + 1) + krow) * HW_ + 32 + 4 * t8];
        }
        bf16x8 a0 = *(const bf16x8*)&w1frag[((kc * 4 + 2 * wm + 0) * 64 + lane) * 8];
        bf16x8 a1 = *(const bf16x8*)&w1frag[((kc * 4 + 2 * wm + 1) * 64 + lane) * 8];
        const int base = buf * (32 * SX);
        bf16x8 b0, b1;
#pragma unroll
        for (int j = 0; j < 8; ++j) {
            b0[j] = xs[base + (8 * g + j) * SX + (2 * wn + 0) * 16 + n];
            b1[j] = xs[base + (8 * g + j) * SX + (2 * wn + 1) * 16 + n];
        }
        acc1[0][0] = __builtin_amdgcn_mfma_f32_16x16x32_bf16(a0, b0, acc1[0][0], 0, 0, 0);
        acc1[0][1] = __builtin_amdgcn_mfma_f32_16x16x32_bf16(a0, b1, acc1[0][1], 0, 0, 0);
        acc1[1][0] = __builtin_amdgcn_mfma_f32_16x16x32_bf16(a1, b0, acc1[1][0], 0, 0, 0);
        acc1[1][1] = __builtin_amdgcn_mfma_f32_16x16x32_bf16(a1, b1, acc1[1][1], 0, 0, 0);

        if (kc < 7) {
            __bf16* d0 = &xs[(buf ^ 1) * (32 * SX) + krow * SX + 4 * t8];
            __bf16* d1 = &xs[(buf ^ 1) * (32 * SX) + krow * SX + 32 + 4 * t8];
            *(bf16x2*)&d0[0] = bf16x2{(__bf16)nf0.x, (__bf16)nf0.y};
            *(bf16x2*)&d0[2] = bf16x2{(__bf16)nf0.z, (__bf16)nf0.w};
            *(bf16x2*)&d1[0] = bf16x2{(__bf16)nf1.x, (__bf16)nf1.y};
            *(bf16x2*)&d1[2] = bf16x2{(__bf16)nf1.z, (__bf16)nf1.w};
        }
        __syncthreads();
    }

    // bias + relu -> hbuf (bf16). D elem: o = Mt*16+4g+j, px = Nt*16+n
#pragma unroll
    for (int m = 0; m < 2; ++m) {
        const int Mo = (2 * wm + m) * 16 + 4 * g;
        float4 bv = *(const float4*)&bias2[Mo];
        float bj[4] = {bv.x, bv.y, bv.z, bv.w};
#pragma unroll
        for (int t = 0; t < 2; ++t) {
            const int px = (2 * wn + t) * 16 + n;
#pragma unroll
            for (int j = 0; j < 4; ++j) {
                hbuf[(Mo + j) * SX + px] = (__bf16)fmaxf(acc1[m][t][j] + bj[j], 0.f);
            }
        }
    }
    __syncthreads();

    // ======================= phase 2 ============================
    f32x4 acc2[9];
#pragma unroll
    for (int m = 0; m < 9; ++m) acc2[m] = f32x4{0.f, 0.f, 0.f, 0.f};

#pragma unroll
    for (int kc2 = 0; kc2 < 2; ++kc2) {
        bf16x8 hb;
#pragma unroll
        for (int j = 0; j < 8; ++j)
            hb[j] = hbuf[(kc2 * 32 + 8 * g + j) * SX + wave * 16 + n];
#pragma unroll
        for (int mt = 0; mt < 9; ++mt) {
            bf16x8 a = *(const bf16x8*)&w2frag[((mt * 2 + kc2) * 64 + lane) * 8];
            acc2[mt] = __builtin_amdgcn_mfma_f32_16x16x32_bf16(a, hb, acc2[mt], 0, 0, 0);
        }
    }

    // store wk (bf16): o2 = mt*16+4g+j, px = wave*16+n
    __bf16* wkb = wk + (size_t)b * KO_ * HW_ + hw0 + wave * 16 + n;
#pragma unroll
    for (int mt = 0; mt < 9; ++mt) {
        const int o0 = mt * 16 + 4 * g;
        float4 bv = *(const float4*)&b2[o0];
        float bj[4] = {bv.x, bv.y, bv.z, bv.w};
#pragma unroll
        for (int j = 0; j < 4; ++j)
            wkb[(size_t)(o0 + j) * HW_] = (__bf16)(acc2[mt][j] + bj[j]);
    }
}

// ---------------------------------------------------------------------------
// involution via LDS-staged x window, conflict-free taps.
// Block = (b, g, 4-row x 128-col tile). Stage 16ch x 6rows x 128px fp32,
// stride 128 (no pads). Aligned b128 per row is contiguous per 32-lane
// row-group = conflict-free. The +-1-shifted taps come from NEIGHBOR LANES
// via __shfl (ds_bpermute, conflict-free) instead of misaligned b32 LDS
// reads (which were 4-way bank conflicts = 7.7M conflict cycles in R9).
// W-edges: q==0 / q==31 select 0 (exact image border zeros).
// Thread = (half=tid>>7, row=(tid>>5)&3, q=tid&31): 8 ch x 4 px.
// ---------------------------------------------------------------------------
__global__ __launch_bounds__(256, 3) void inv_kernel(const float* __restrict__ x,
                                                     const __bf16* __restrict__ wkb,
                                                     float* __restrict__ out) {
    __shared__ float lds[96 * 128];                  // 48 KB
    const int bi   = blockIdx.x;
    const int tile = bi & 31;
    const int g    = (bi >> 5) & 15;
    const int b    = bi >> 9;
    const int h0   = tile * 4;
    const int tid  = threadIdx.x;
    const int lane = tid & 63;

    // ---- stage x window: rows h0-1 .. h0+4, 16 channels, zero H-edges ----
    const float* xg = x + ((size_t)b * C_ + g * GC_) * HW_;
#pragma unroll
    for (int i = 0; i < 12; ++i) {
        int s = tid + 256 * i;                       // 0..3071
        int chrow = s >> 5, f4 = s & 31;
        int ch = chrow / 6, row = chrow - 6 * ch;
        int gh = h0 - 1 + row;
        float4 v = {0.f, 0.f, 0.f, 0.f};
        if (gh >= 0 && gh < H_)
            v = *(const float4*)&xg[((size_t)ch * H_ + gh) * W_ + f4 * 4];
        *(float4*)&lds[chrow * 128 + f4 * 4] = v;
    }
    __syncthreads();

    // ---- compute: thread = (half=tid>>7, row=(tid>>5)&3, quad=tid&31) ----
    const int q    = tid & 31;
    const int row  = (tid >> 5) & 3;
    const int half = tid >> 7;
    const int w0   = q * 4;
    const int hh   = h0 + row;
    const bool ql  = (q == 0);
    const bool qr  = (q == 31);

    // wk: 9 taps for this row-quad (bf16 -> fp32), reused over 8 channels
    float4 wk4[9];
    const __bf16* wkp = wkb + ((size_t)b * KO_ + g * 9) * HW_ + hh * W_ + w0;
#pragma unroll
    for (int k = 0; k < 9; ++k) {
        bf16x4 v = *(const bf16x4*)&wkp[(size_t)k * HW_];
        wk4[k] = float4{(float)v[0], (float)v[1], (float)v[2], (float)v[3]};
    }

    float* op = out + ((size_t)b * C_ + g * GC_ + half * 8) * HW_ + hh * W_ + w0;

#pragma unroll
    for (int cc = 0; cc < 8; ++cc) {
        const int ch = half * 8 + cc;
        const float* base = &lds[(ch * 6 + row) * 128 + w0];
        float4 acc = {0.f, 0.f, 0.f, 0.f};
#pragma unroll
        for (int dr = 0; dr < 3; ++dr) {
            float4 c = *(const float4*)(base + dr * 128);   // ds_read_b128, conflict-free
            float lms = __shfl(c.w, lane - 1);              // neighbor's last elem
            float rms = __shfl(c.x, lane + 1);              // neighbor's first elem
            float lm = ql ? 0.f : lms;
            float rm = qr ? 0.f : rms;
            float4 t0 = wk4[3 * dr + 0];
            float4 t1 = wk4[3 * dr + 1];
            float4 t2 = wk4[3 * dr + 2];
            acc.x = fmaf(t0.x, lm,  acc.x);
            acc.y = fmaf(t0.y, c.x, acc.y);
            acc.z = fmaf(t0.z, c.y, acc.z);
            acc.w = fmaf(t0.w, c.z, acc.w);
            acc.x = fmaf(t1.x, c.x, acc.x);
            acc.y = fmaf(t1.y, c.y, acc.y);
            acc.z = fmaf(t1.z, c.z, acc.z);
            acc.w = fmaf(t1.w, c.w, acc.w);
            acc.x = fmaf(t2.x, c.y, acc.x);
            acc.y = fmaf(t2.y, c.z, acc.y);
            acc.z = fmaf(t2.z, c.w, acc.z);
            acc.w = fmaf(t2.w, rm,  acc.w);
        }
        *(float4*)&op[(size_t)cc * HW_] = acc;
    }
}

// ---------------------------------------------------------------------------
extern "C" void kernel_launch(void* const* d_in, const int* in_sizes, int n_in,
                              void* d_out, int out_size, void* d_ws, size_t ws_size,
                              hipStream_t stream) {
    const float* x     = (const float*)d_in[0];
    const float* w1    = (const float*)d_in[1];
    const float* gamma = (const float*)d_in[2];
    const float* beta  = (const float*)d_in[3];
    const float* mean  = (const float*)d_in[4];
    const float* var   = (const float*)d_in[5];
    const float* w2    = (const float*)d_in[6];
    const float* b2    = (const float*)d_in[7];
    float* out = (float*)d_out;

    char* ws = (char*)d_ws;
    __bf16* w1frag = (__bf16*)(ws);                 // 32 KB [8][4][64][8]
    __bf16* w2frag = (__bf16*)(ws + (32 << 10));    // 18 KB [9][2][64][8]
    float*  bias2  = (float*)(ws + (56 << 10));     // 256 B
    __bf16* wkbuf  = (__bf16*)(ws + (1 << 20));     // 18 MB [B][144][HW] bf16

    hipLaunchKernelGGL(prep_kernel, dim3(100), dim3(256), 0, stream,
                       w1, gamma, beta, mean, var, w2, w1frag, w2frag, bias2);
    hipLaunchKernelGGL(conv12_kernel, dim3(1024), dim3(256), 0, stream,
                       x, w1frag, bias2, w2frag, b2, wkbuf);
    hipLaunchKernelGGL(inv_kernel, dim3(2048), dim3(256), 0, stream,
                       x, wkbuf, out);
}

// Round 15
// 57.623 us; speedup vs baseline: 1.3229x; 1.0077x over previous
//
#include <hip/hip_runtime.h>

#define B_   4
#define C_   256
#define CR_  64
#define H_   128
#define W_   128
#define HW_  (H_ * W_)
#define G_   16
#define GC_  16
#define KO_  144   // K*K*G = 9*16
#define EPS_ 1e-5f

typedef __bf16 bf16x8 __attribute__((ext_vector_type(8)));
typedef __bf16 bf16x4 __attribute__((ext_vector_type(4)));
typedef __bf16 bf16x2 __attribute__((ext_vector_type(2)));
typedef float  f32x4  __attribute__((ext_vector_type(4)));

#define SX 66   // LDS row stride (elements) for xs/hbuf: banks 2-way on gathers

// ---------------------------------------------------------------------------
// prep: build MFMA A-fragments (lane order: m = lane&15, kslot = 8*(lane>>4)+j;
// the kslot permutation cancels between A and B since both use it).
// ---------------------------------------------------------------------------
__global__ void prep_kernel(const float* __restrict__ w1,
                            const float* __restrict__ gamma,
                            const float* __restrict__ beta,
                            const float* __restrict__ mean,
                            const float* __restrict__ var,
                            const float* __restrict__ w2,
                            __bf16* __restrict__ w1frag,
                            __bf16* __restrict__ w2frag,
                            float* __restrict__ bias2) {
    int idx = blockIdx.x * 256 + threadIdx.x;
    if (idx < 16384) {                      // w1frag: [8 kc][4 mt][64 l][8 j]
        int kc = idx >> 11, r = idx & 2047;
        int mt = r >> 9, l = (r >> 3) & 63, j = r & 7;
        int o = mt * 16 + (l & 15);
        int c = kc * 32 + 8 * (l >> 4) + j;
        float alpha = gamma[o] * rsqrtf(var[o] + EPS_);
        w1frag[idx] = (__bf16)(w1[o * C_ + c] * alpha);
        if (idx < CR_) {
            float a2 = gamma[idx] * rsqrtf(var[idx] + EPS_);
            bias2[idx] = beta[idx] - mean[idx] * a2;
        }
    } else if (idx < 16384 + 9216) {        // w2frag: [9 mt][2 kc2][64 l][8 j]
        int i2 = idx - 16384;
        int mt = i2 >> 10, r = i2 & 1023;
        int kc2 = r >> 9, l = (r >> 3) & 63, j = r & 7;
        int o2 = mt * 16 + (l & 15);
        int cc = kc2 * 32 + 8 * (l >> 4) + j;
        w2frag[i2] = (__bf16)(w2[o2 * CR_ + cc]);
    }
}

// ---------------------------------------------------------------------------
// fused conv1(+BN+ReLU) + conv2 via bf16 MFMA, fp32 accumulate.
// wk stored as bf16. (unchanged — ~21 us)
// ---------------------------------------------------------------------------
__global__ __launch_bounds__(256, 4) void conv12_kernel(
        const float* __restrict__ x,
        const __bf16* __restrict__ w1frag,
        const float* __restrict__ bias2,
        const __bf16* __restrict__ w2frag,
        const float* __restrict__ b2,
        __bf16* __restrict__ wk) {
    __shared__ __bf16 xs[2 * 32 * SX];     // 8.4 KB double-buffered x chunk
    __shared__ __bf16 hbuf[CR_ * SX];      // 8.4 KB h tile (bf16)

    const int tid  = threadIdx.x;
    const int lane = tid & 63;
    const int wave = tid >> 6;
    const int wm = wave >> 1, wn = wave & 1;
    const int g = lane >> 4, n = lane & 15;

    const int px0 = blockIdx.x * 64;
    const int b   = px0 >> 14;
    const int hw0 = px0 & (HW_ - 1);

    const float* xb = x + (size_t)b * C_ * HW_ + hw0;
    const int krow = tid >> 3;             // 0..31 (k row within chunk)
    const int t8   = tid & 7;              // 0..7

    // ---- stage chunk 0 into buf 0 ----
    {
        float4 v0 = *(const float4*)&xb[(size_t)krow * HW_ + 4 * t8];
        float4 v1 = *(const float4*)&xb[(size_t)krow * HW_ + 32 + 4 * t8];
        __bf16* d0 = &xs[krow * SX + 4 * t8];
        __bf16* d1 = &xs[krow * SX + 32 + 4 * t8];
        *(bf16x2*)&d0[0] = bf16x2{(__bf16)v0.x, (__bf16)v0.y};
        *(bf16x2*)&d0[2] = bf16x2{(__bf16)v0.z, (__bf16)v0.w};
        *(bf16x2*)&d1[0] = bf16x2{(__bf16)v1.x, (__bf16)v1.y};
        *(bf16x2*)&d1[2] = bf16x2{(__bf16)v1.z, (__bf16)v1.w};
    }
    __syncthreads();

    // ======================= phase 1 ============================
    f32x4 acc1[2][2];
#pragma unroll
    for (int m = 0; m < 2; ++m)
#pragma unroll
        for (int t = 0; t < 2; ++t) acc1[m][t] = f32x4{0.f, 0.f, 0.f, 0.f};

    for (int kc = 0; kc < 8; ++kc) {
        const int buf = kc & 1;
        float4 nf0, nf1;
        if (kc < 7) {   // issue next chunk's loads early (hide HBM latency)
            nf0 = *(const float4*)&xb[(size_t)(32 * (kc + 1) + krow) * HW_ + 4 * t8];
            nf1 = *(const float4*)&xb[(size_t)(32 * (kc + 1) + krow) * HW_ + 32 + 4 * t8];
        }
        bf16x8 a0 = *(const bf16x8*)&w1frag[((kc * 4 + 2 * wm + 0) * 64 + lane) * 8];
        bf16x8 a1 = *(const bf16x8*)&w1frag[((kc * 4 + 2 * wm + 1) * 64 + lane) * 8];
        const int base = buf * (32 * SX);
        bf16x8 b0, b1;
#pragma unroll
        for (int j = 0; j < 8; ++j) {
            b0[j] = xs[base + (8 * g + j) * SX + (2 * wn + 0) * 16 + n];
            b1[j] = xs[base + (8 * g + j) * SX + (2 * wn + 1) * 16 + n];
        }
        acc1[0][0] = __builtin_amdgcn_mfma_f32_16x16x32_bf16(a0, b0, acc1[0][0], 0, 0, 0);
        acc1[0][1] = __builtin_amdgcn_mfma_f32_16x16x32_bf16(a0, b1, acc1[0][1], 0, 0, 0);
        acc1[1][0] = __builtin_amdgcn_mfma_f32_16x16x32_bf16(a1, b0, acc1[1][0], 0, 0, 0);
        acc1[1][1] = __builtin_amdgcn_mfma_f32_16x16x32_bf16(a1, b1, acc1[1][1], 0, 0, 0);

        if (kc < 7) {
            __bf16* d0 = &xs[(buf ^ 1) * (32 * SX) + krow * SX + 4 * t8];
            __bf16* d1 = &xs[(buf ^ 1) * (32 * SX) + krow * SX + 32 + 4 * t8];
            *(bf16x2*)&d0[0] = bf16x2{(__bf16)nf0.x, (__bf16)nf0.y};
            *(bf16x2*)&d0[2] = bf16x2{(__bf16)nf0.z, (__bf16)nf0.w};
            *(bf16x2*)&d1[0] = bf16x2{(__bf16)nf1.x, (__bf16)nf1.y};
            *(bf16x2*)&d1[2] = bf16x2{(__bf16)nf1.z, (__bf16)nf1.w};
        }
        __syncthreads();
    }

    // bias + relu -> hbuf (bf16). D elem: o = Mt*16+4g+j, px = Nt*16+n
#pragma unroll
    for (int m = 0; m < 2; ++m) {
        const int Mo = (2 * wm + m) * 16 + 4 * g;
        float4 bv = *(const float4*)&bias2[Mo];
        float bj[4] = {bv.x, bv.y, bv.z, bv.w};
#pragma unroll
        for (int t = 0; t < 2; ++t) {
            const int px = (2 * wn + t) * 16 + n;
#pragma unroll
            for (int j = 0; j < 4; ++j) {
                hbuf[(Mo + j) * SX + px] = (__bf16)fmaxf(acc1[m][t][j] + bj[j], 0.f);
            }
        }
    }
    __syncthreads();

    // ======================= phase 2 ============================
    f32x4 acc2[9];
#pragma unroll
    for (int m = 0; m < 9; ++m) acc2[m] = f32x4{0.f, 0.f, 0.f, 0.f};

#pragma unroll
    for (int kc2 = 0; kc2 < 2; ++kc2) {
        bf16x8 hb;
#pragma unroll
        for (int j = 0; j < 8; ++j)
            hb[j] = hbuf[(kc2 * 32 + 8 * g + j) * SX + wave * 16 + n];
#pragma unroll
        for (int mt = 0; mt < 9; ++mt) {
            bf16x8 a = *(const bf16x8*)&w2frag[((mt * 2 + kc2) * 64 + lane) * 8];
            acc2[mt] = __builtin_amdgcn_mfma_f32_16x16x32_bf16(a, hb, acc2[mt], 0, 0, 0);
        }
    }

    // store wk (bf16): o2 = mt*16+4g+j, px = wave*16+n
    __bf16* wkb = wk + (size_t)b * KO_ * HW_ + hw0 + wave * 16 + n;
#pragma unroll
    for (int mt = 0; mt < 9; ++mt) {
        const int o0 = mt * 16 + 4 * g;
        float4 bv = *(const float4*)&b2[o0];
        float bj[4] = {bv.x, bv.y, bv.z, bv.w};
#pragma unroll
        for (int j = 0; j < 4; ++j)
            wkb[(size_t)(o0 + j) * HW_] = (__bf16)(acc2[mt][j] + bj[j]);
    }
}

// ---------------------------------------------------------------------------
// involution via bf16 LDS-staged x window, conflict-free taps.
// Block = (b, g, 4-row x 128-col tile). Stage 16ch x 6rows x 128px as BF16
// (24 KB -> 6 blocks/CU, double R10's occupancy; LDS bytes halved).
// Global reads stay fp32 float4 (HBM bytes unchanged); convert on LDS write.
// Taps: ds_read_b64 (4x bf16) per row, conflict-free (lane n -> bank 2n%32,
// 2-way = free); +-1 edges from neighbor lanes via __shfl as in R10.
// Precision: one extra bf16 rounding on x taps (~+0.1 absmax, budget 0.415).
// Thread = (half=tid>>7, row=(tid>>5)&3, q=tid&31): 8 ch x 4 px.
// ---------------------------------------------------------------------------
__global__ __launch_bounds__(256, 6) void inv_kernel(const float* __restrict__ x,
                                                     const __bf16* __restrict__ wkb,
                                                     float* __restrict__ out) {
    __shared__ __bf16 lds[96 * 128];                 // 24 KB
    const int bi   = blockIdx.x;
    const int tile = bi & 31;
    const int g    = (bi >> 5) & 15;
    const int b    = bi >> 9;
    const int h0   = tile * 4;
    const int tid  = threadIdx.x;
    const int lane = tid & 63;

    // ---- stage x window: rows h0-1 .. h0+4, 16 channels, zero H-edges ----
    const float* xg = x + ((size_t)b * C_ + g * GC_) * HW_;
#pragma unroll
    for (int i = 0; i < 12; ++i) {
        int s = tid + 256 * i;                       // 0..3071
        int chrow = s >> 5, f4 = s & 31;
        int ch = chrow / 6, row = chrow - 6 * ch;
        int gh = h0 - 1 + row;
        float4 v = {0.f, 0.f, 0.f, 0.f};
        if (gh >= 0 && gh < H_)
            v = *(const float4*)&xg[((size_t)ch * H_ + gh) * W_ + f4 * 4];
        *(bf16x4*)&lds[chrow * 128 + f4 * 4] =
            bf16x4{(__bf16)v.x, (__bf16)v.y, (__bf16)v.z, (__bf16)v.w};
    }
    __syncthreads();

    // ---- compute: thread = (half=tid>>7, row=(tid>>5)&3, quad=tid&31) ----
    const int q    = tid & 31;
    const int row  = (tid >> 5) & 3;
    const int half = tid >> 7;
    const int w0   = q * 4;
    const int hh   = h0 + row;
    const bool ql  = (q == 0);
    const bool qr  = (q == 31);

    // wk: 9 taps for this row-quad (bf16 -> fp32), reused over 8 channels
    float4 wk4[9];
    const __bf16* wkp = wkb + ((size_t)b * KO_ + g * 9) * HW_ + hh * W_ + w0;
#pragma unroll
    for (int k = 0; k < 9; ++k) {
        bf16x4 v = *(const bf16x4*)&wkp[(size_t)k * HW_];
        wk4[k] = float4{(float)v[0], (float)v[1], (float)v[2], (float)v[3]};
    }

    float* op = out + ((size_t)b * C_ + g * GC_ + half * 8) * HW_ + hh * W_ + w0;

#pragma unroll
    for (int cc = 0; cc < 8; ++cc) {
        const int ch = half * 8 + cc;
        const __bf16* base = &lds[(ch * 6 + row) * 128 + w0];
        float4 acc = {0.f, 0.f, 0.f, 0.f};
#pragma unroll
        for (int dr = 0; dr < 3; ++dr) {
            bf16x4 cv = *(const bf16x4*)(base + dr * 128);  // ds_read_b64
            float4 c = {(float)cv[0], (float)cv[1], (float)cv[2], (float)cv[3]};
            float lms = __shfl(c.w, lane - 1);              // neighbor's last elem
            float rms = __shfl(c.x, lane + 1);              // neighbor's first elem
            float lm = ql ? 0.f : lms;
            float rm = qr ? 0.f : rms;
            float4 t0 = wk4[3 * dr + 0];
            float4 t1 = wk4[3 * dr + 1];
            float4 t2 = wk4[3 * dr + 2];
            acc.x = fmaf(t0.x, lm,  acc.x);
            acc.y = fmaf(t0.y, c.x, acc.y);
            acc.z = fmaf(t0.z, c.y, acc.z);
            acc.w = fmaf(t0.w, c.z, acc.w);
            acc.x = fmaf(t1.x, c.x, acc.x);
            acc.y = fmaf(t1.y, c.y, acc.y);
            acc.z = fmaf(t1.z, c.z, acc.z);
            acc.w = fmaf(t1.w, c.w, acc.w);
            acc.x = fmaf(t2.x, c.y, acc.x);
            acc.y = fmaf(t2.y, c.z, acc.y);
            acc.z = fmaf(t2.z, c.w, acc.z);
            acc.w = fmaf(t2.w, rm,  acc.w);
        }
        *(float4*)&op[(size_t)cc * HW_] = acc;
    }
}

// ---------------------------------------------------------------------------
extern "C" void kernel_launch(void* const* d_in, const int* in_sizes, int n_in,
                              void* d_out, int out_size, void* d_ws, size_t ws_size,
                              hipStream_t stream) {
    const float* x     = (const float*)d_in[0];
    const float* w1    = (const float*)d_in[1];
    const float* gamma = (const float*)d_in[2];
    const float* beta  = (const float*)d_in[3];
    const float* mean  = (const float*)d_in[4];
    const float* var   = (const float*)d_in[5];
    const float* w2    = (const float*)d_in[6];
    const float* b2    = (const float*)d_in[7];
    float* out = (float*)d_out;

    char* ws = (char*)d_ws;
    __bf16* w1frag = (__bf16*)(ws);                 // 32 KB [8][4][64][8]
    __bf16* w2frag = (__bf16*)(ws + (32 << 10));    // 18 KB [9][2][64][8]
    float*  bias2  = (float*)(ws + (56 << 10));     // 256 B
    __bf16* wkbuf  = (__bf16*)(ws + (1 << 20));     // 18 MB [B][144][HW] bf16

    hipLaunchKernelGGL(prep_kernel, dim3(100), dim3(256), 0, stream,
                       w1, gamma, beta, mean, var, w2, w1frag, w2frag, bias2);
    hipLaunchKernelGGL(conv12_kernel, dim3(1024), dim3(256), 0, stream,
                       x, w1frag, bias2, w2frag, b2, wkbuf);
    hipLaunchKernelGGL(inv_kernel, dim3(2048), dim3(256), 0, stream,
                       x, wkbuf, out);
}

// Round 17
// 51.517 us; speedup vs baseline: 1.4796x; 1.1185x over previous
//
#include <hip/hip_runtime.h>

#define B_   4
#define C_   256
#define CR_  64
#define H_   128
#define W_   128
#define HW_  (H_ * W_)
#define G_   16
#define GC_  16
#define KO_  144   // K*K*G = 9*16
#define EPS_ 1e-5f

typedef __bf16 bf16x8 __attribute__((ext_vector_type(8)));
typedef __bf16 bf16x4 __attribute__((ext_vector_type(4)));
typedef __bf16 bf16x2 __attribute__((ext_vector_type(2)));
typedef float  f32x4  __attribute__((ext_vector_type(4)));

#define SX 66   // LDS row stride (elements) for xs/hbuf: banks 2-way on gathers

// ---------------------------------------------------------------------------
// prep: build MFMA A-fragments (lane order: m = lane&15, kslot = 8*(lane>>4)+j;
// the kslot permutation cancels between A and B since both use it).
// ---------------------------------------------------------------------------
__global__ void prep_kernel(const float* __restrict__ w1,
                            const float* __restrict__ gamma,
                            const float* __restrict__ beta,
                            const float* __restrict__ mean,
                            const float* __restrict__ var,
                            const float* __restrict__ w2,
                            __bf16* __restrict__ w1frag,
                            __bf16* __restrict__ w2frag,
                            float* __restrict__ bias2) {
    int idx = blockIdx.x * 256 + threadIdx.x;
    if (idx < 16384) {                      // w1frag: [8 kc][4 mt][64 l][8 j]
        int kc = idx >> 11, r = idx & 2047;
        int mt = r >> 9, l = (r >> 3) & 63, j = r & 7;
        int o = mt * 16 + (l & 15);
        int c = kc * 32 + 8 * (l >> 4) + j;
        float alpha = gamma[o] * rsqrtf(var[o] + EPS_);
        w1frag[idx] = (__bf16)(w1[o * C_ + c] * alpha);
        if (idx < CR_) {
            float a2 = gamma[idx] * rsqrtf(var[idx] + EPS_);
            bias2[idx] = beta[idx] - mean[idx] * a2;
        }
    } else if (idx < 16384 + 9216) {        // w2frag: [9 mt][2 kc2][64 l][8 j]
        int i2 = idx - 16384;
        int mt = i2 >> 10, r = i2 & 1023;
        int kc2 = r >> 9, l = (r >> 3) & 63, j = r & 7;
        int o2 = mt * 16 + (l & 15);
        int cc = kc2 * 32 + 8 * (l >> 4) + j;
        w2frag[i2] = (__bf16)(w2[o2 * CR_ + cc]);
    }
}

// ---------------------------------------------------------------------------
// fused conv1(+BN+ReLU) + conv2 via bf16 MFMA, fp32 accumulate.
// wk stored as bf16. XCD-swizzled blockIdx (1024 = 8 XCD x 128 contiguous
// tiles each -> neighboring pixel tiles share the same per-XCD L2).
// ---------------------------------------------------------------------------
__global__ __launch_bounds__(256, 4) void conv12_kernel(
        const float* __restrict__ x,
        const __bf16* __restrict__ w1frag,
        const float* __restrict__ bias2,
        const __bf16* __restrict__ w2frag,
        const float* __restrict__ b2,
        __bf16* __restrict__ wk) {
    __shared__ __bf16 xs[2 * 32 * SX];     // 8.4 KB double-buffered x chunk
    __shared__ __bf16 hbuf[CR_ * SX];      // 8.4 KB h tile (bf16)

    const int tid  = threadIdx.x;
    const int lane = tid & 63;
    const int wave = tid >> 6;
    const int wm = wave >> 1, wn = wave & 1;
    const int g = lane >> 4, n = lane & 15;

    // XCD-aware bijective swizzle: launched%8 = XCD -> contiguous tile range
    const int bid = (blockIdx.x & 7) * 128 + (blockIdx.x >> 3);
    const int px0 = bid * 64;
    const int b   = px0 >> 14;
    const int hw0 = px0 & (HW_ - 1);

    const float* xb = x + (size_t)b * C_ * HW_ + hw0;
    const int krow = tid >> 3;             // 0..31 (k row within chunk)
    const int t8   = tid & 7;              // 0..7

    // ---- stage chunk 0 into buf 0 ----
    {
        float4 v0 = *(const float4*)&xb[(size_t)krow * HW_ + 4 * t8];
        float4 v1 = *(const float4*)&xb[(size_t)krow * HW_ + 32 + 4 * t8];
        __bf16* d0 = &xs[krow * SX + 4 * t8];
        __bf16* d1 = &xs[krow * SX + 32 + 4 * t8];
        *(bf16x2*)&d0[0] = bf16x2{(__bf16)v0.x, (__bf16)v0.y};
        *(bf16x2*)&d0[2] = bf16x2{(__bf16)v0.z, (__bf16)v0.w};
        *(bf16x2*)&d1[0] = bf16x2{(__bf16)v1.x, (__bf16)v1.y};
        *(bf16x2*)&d1[2] = bf16x2{(__bf16)v1.z, (__bf16)v1.w};
    }
    __syncthreads();

    // ======================= phase 1 ============================
    f32x4 acc1[2][2];
#pragma unroll
    for (int m = 0; m < 2; ++m)
#pragma unroll
        for (int t = 0; t < 2; ++t) acc1[m][t] = f32x4{0.f, 0.f, 0.f, 0.f};

    for (int kc = 0; kc < 8; ++kc) {
        const int buf = kc & 1;
        float4 nf0, nf1;
        if (kc < 7) {   // issue next chunk's loads early (hide HBM latency)
            nf0 = *(const float4*)&xb[(size_t)(32 * (kc + 1) + krow) * HW_ + 4 * t8];
            nf1 = *(const float4*)&xb[(size_t)(32 * (kc + 1) + krow) * HW_ + 32 + 4 * t8];
        }
        bf16x8 a0 = *(const bf16x8*)&w1frag[((kc * 4 + 2 * wm + 0) * 64 + lane) * 8];
        bf16x8 a1 = *(const bf16x8*)&w1frag[((kc * 4 + 2 * wm + 1) * 64 + lane) * 8];
        const int base = buf * (32 * SX);
        bf16x8 b0, b1;
#pragma unroll
        for (int j = 0; j < 8; ++j) {
            b0[j] = xs[base + (8 * g + j) * SX + (2 * wn + 0) * 16 + n];
            b1[j] = xs[base + (8 * g + j) * SX + (2 * wn + 1) * 16 + n];
        }
        acc1[0][0] = __builtin_amdgcn_mfma_f32_16x16x32_bf16(a0, b0, acc1[0][0], 0, 0, 0);
        acc1[0][1] = __builtin_amdgcn_mfma_f32_16x16x32_bf16(a0, b1, acc1[0][1], 0, 0, 0);
        acc1[1][0] = __builtin_amdgcn_mfma_f32_16x16x32_bf16(a1, b0, acc1[1][0], 0, 0, 0);
        acc1[1][1] = __builtin_amdgcn_mfma_f32_16x16x32_bf16(a1, b1, acc1[1][1], 0, 0, 0);

        if (kc < 7) {
            __bf16* d0 = &xs[(buf ^ 1) * (32 * SX) + krow * SX + 4 * t8];
            __bf16* d1 = &xs[(buf ^ 1) * (32 * SX) + krow * SX + 32 + 4 * t8];
            *(bf16x2*)&d0[0] = bf16x2{(__bf16)nf0.x, (__bf16)nf0.y};
            *(bf16x2*)&d0[2] = bf16x2{(__bf16)nf0.z, (__bf16)nf0.w};
            *(bf16x2*)&d1[0] = bf16x2{(__bf16)nf1.x, (__bf16)nf1.y};
            *(bf16x2*)&d1[2] = bf16x2{(__bf16)nf1.z, (__bf16)nf1.w};
        }
        __syncthreads();
    }

    // bias + relu -> hbuf (bf16). D elem: o = Mt*16+4g+j, px = Nt*16+n
#pragma unroll
    for (int m = 0; m < 2; ++m) {
        const int Mo = (2 * wm + m) * 16 + 4 * g;
        float4 bv = *(const float4*)&bias2[Mo];
        float bj[4] = {bv.x, bv.y, bv.z, bv.w};
#pragma unroll
        for (int t = 0; t < 2; ++t) {
            const int px = (2 * wn + t) * 16 + n;
#pragma unroll
            for (int j = 0; j < 4; ++j) {
                hbuf[(Mo + j) * SX + px] = (__bf16)fmaxf(acc1[m][t][j] + bj[j], 0.f);
            }
        }
    }
    __syncthreads();

    // ======================= phase 2 ============================
    f32x4 acc2[9];
#pragma unroll
    for (int m = 0; m < 9; ++m) acc2[m] = f32x4{0.f, 0.f, 0.f, 0.f};

#pragma unroll
    for (int kc2 = 0; kc2 < 2; ++kc2) {
        bf16x8 hb;
#pragma unroll
        for (int j = 0; j < 8; ++j)
            hb[j] = hbuf[(kc2 * 32 + 8 * g + j) * SX + wave * 16 + n];
#pragma unroll
        for (int mt = 0; mt < 9; ++mt) {
            bf16x8 a = *(const bf16x8*)&w2frag[((mt * 2 + kc2) * 64 + lane) * 8];
            acc2[mt] = __builtin_amdgcn_mfma_f32_16x16x32_bf16(a, hb, acc2[mt], 0, 0, 0);
        }
    }

    // store wk (bf16, cached — inv reads it back soon): o2 = mt*16+4g+j
    __bf16* wkb = wk + (size_t)b * KO_ * HW_ + hw0 + wave * 16 + n;
#pragma unroll
    for (int mt = 0; mt < 9; ++mt) {
        const int o0 = mt * 16 + 4 * g;
        float4 bv = *(const float4*)&b2[o0];
        float bj[4] = {bv.x, bv.y, bv.z, bv.w};
#pragma unroll
        for (int j = 0; j < 4; ++j)
            wkb[(size_t)(o0 + j) * HW_] = (__bf16)(acc2[mt][j] + bj[j]);
    }
}

// ---------------------------------------------------------------------------
// involution via bf16 LDS-staged x window, conflict-free taps.
// XCD-swizzled blockIdx (2048 = 8 x 256): tiles of the same (b,g) stay on
// one XCD -> shared halo rows + wk segments hit the same L2.
// out written with NON-TEMPORAL stores (never re-read; keeps L2 for x/wk).
// ---------------------------------------------------------------------------
__global__ __launch_bounds__(256, 6) void inv_kernel(const float* __restrict__ x,
                                                     const __bf16* __restrict__ wkb,
                                                     float* __restrict__ out) {
    __shared__ __bf16 lds[96 * 128];                 // 24 KB
    const int bi   = (blockIdx.x & 7) * 256 + (blockIdx.x >> 3);  // XCD swizzle
    const int tile = bi & 31;
    const int g    = (bi >> 5) & 15;
    const int b    = bi >> 9;
    const int h0   = tile * 4;
    const int tid  = threadIdx.x;
    const int lane = tid & 63;

    // ---- stage x window: rows h0-1 .. h0+4, 16 channels, zero H-edges ----
    const float* xg = x + ((size_t)b * C_ + g * GC_) * HW_;
#pragma unroll
    for (int i = 0; i < 12; ++i) {
        int s = tid + 256 * i;                       // 0..3071
        int chrow = s >> 5, f4 = s & 31;
        int ch = chrow / 6, row = chrow - 6 * ch;
        int gh = h0 - 1 + row;
        float4 v = {0.f, 0.f, 0.f, 0.f};
        if (gh >= 0 && gh < H_)
            v = *(const float4*)&xg[((size_t)ch * H_ + gh) * W_ + f4 * 4];
        *(bf16x4*)&lds[chrow * 128 + f4 * 4] =
            bf16x4{(__bf16)v.x, (__bf16)v.y, (__bf16)v.z, (__bf16)v.w};
    }
    __syncthreads();

    // ---- compute: thread = (half=tid>>7, row=(tid>>5)&3, quad=tid&31) ----
    const int q    = tid & 31;
    const int row  = (tid >> 5) & 3;
    const int half = tid >> 7;
    const int w0   = q * 4;
    const int hh   = h0 + row;
    const bool ql  = (q == 0);
    const bool qr  = (q == 31);

    // wk: 9 taps for this row-quad (bf16 -> fp32), reused over 8 channels
    float4 wk4[9];
    const __bf16* wkp = wkb + ((size_t)b * KO_ + g * 9) * HW_ + hh * W_ + w0;
#pragma unroll
    for (int k = 0; k < 9; ++k) {
        bf16x4 v = *(const bf16x4*)&wkp[(size_t)k * HW_];
        wk4[k] = float4{(float)v[0], (float)v[1], (float)v[2], (float)v[3]};
    }

    float* op = out + ((size_t)b * C_ + g * GC_ + half * 8) * HW_ + hh * W_ + w0;

#pragma unroll
    for (int cc = 0; cc < 8; ++cc) {
        const int ch = half * 8 + cc;
        const __bf16* base = &lds[(ch * 6 + row) * 128 + w0];
        float4 acc = {0.f, 0.f, 0.f, 0.f};
#pragma unroll
        for (int dr = 0; dr < 3; ++dr) {
            bf16x4 cv = *(const bf16x4*)(base + dr * 128);  // ds_read_b64
            float4 c = {(float)cv[0], (float)cv[1], (float)cv[2], (float)cv[3]};
            float lms = __shfl(c.w, lane - 1);              // neighbor's last elem
            float rms = __shfl(c.x, lane + 1);              // neighbor's first elem
            float lm = ql ? 0.f : lms;
            float rm = qr ? 0.f : rms;
            float4 t0 = wk4[3 * dr + 0];
            float4 t1 = wk4[3 * dr + 1];
            float4 t2 = wk4[3 * dr + 2];
            acc.x = fmaf(t0.x, lm,  acc.x);
            acc.y = fmaf(t0.y, c.x, acc.y);
            acc.z = fmaf(t0.z, c.y, acc.z);
            acc.w = fmaf(t0.w, c.z, acc.w);
            acc.x = fmaf(t1.x, c.x, acc.x);
            acc.y = fmaf(t1.y, c.y, acc.y);
            acc.z = fmaf(t1.z, c.z, acc.z);
            acc.w = fmaf(t1.w, c.w, acc.w);
            acc.x = fmaf(t2.x, c.y, acc.x);
            acc.y = fmaf(t2.y, c.z, acc.y);
            acc.z = fmaf(t2.z, c.w, acc.z);
            acc.w = fmaf(t2.w, rm,  acc.w);
        }
        // non-temporal store via ext-vector type (builtin rejects HIP float4)
        f32x4 av = {acc.x, acc.y, acc.z, acc.w};
        __builtin_nontemporal_store(av, (f32x4*)&op[(size_t)cc * HW_]);
    }
}

// ---------------------------------------------------------------------------
extern "C" void kernel_launch(void* const* d_in, const int* in_sizes, int n_in,
                              void* d_out, int out_size, void* d_ws, size_t ws_size,
                              hipStream_t stream) {
    const float* x     = (const float*)d_in[0];
    const float* w1    = (const float*)d_in[1];
    const float* gamma = (const float*)d_in[2];
    const float* beta  = (const float*)d_in[3];
    const float* mean  = (const float*)d_in[4];
    const float* var   = (const float*)d_in[5];
    const float* w2    = (const float*)d_in[6];
    const float* b2    = (const float*)d_in[7];
    float* out = (float*)d_out;

    char* ws = (char*)d_ws;
    __bf16* w1frag = (__bf16*)(ws);                 // 32 KB [8][4][64][8]
    __bf16* w2frag = (__bf16*)(ws + (32 << 10));    // 18 KB [9][2][64][8]
    float*  bias2  = (float*)(ws + (56 << 10));     // 256 B
    __bf16* wkbuf  = (__bf16*)(ws + (1 << 20));     // 18 MB [B][144][HW] bf16

    hipLaunchKernelGGL(prep_kernel, dim3(100), dim3(256), 0, stream,
                       w1, gamma, beta, mean, var, w2, w1frag, w2frag, bias2);
    hipLaunchKernelGGL(conv12_kernel, dim3(1024), dim3(256), 0, stream,
                       x, w1frag, bias2, w2frag, b2, wkbuf);
    hipLaunchKernelGGL(inv_kernel, dim3(2048), dim3(256), 0, stream,
                       x, wkbuf, out);
}